// Round 4
// baseline (309.046 us; speedup 1.0000x reference)
//
#include <hip/hip_runtime.h>
#include <hip/hip_bf16.h>
#include <cstdio>

typedef __attribute__((ext_vector_type(8))) short short8;
typedef __attribute__((ext_vector_type(8))) unsigned short ushort8;
typedef __attribute__((ext_vector_type(4))) float f32x4;
typedef __attribute__((ext_vector_type(4))) unsigned short ushort4v;

__device__ inline unsigned short f2bf(float f){
    unsigned int u = __float_as_uint(f);
    unsigned int r = (u + 0x7fffu + ((u >> 16) & 1u)) >> 16;
    return (unsigned short)r;
}
__device__ inline float bf2f(unsigned short b){
    return __uint_as_float((unsigned int)b << 16);
}

__device__ inline void store1(float* p, float v){ *p = v; }
__device__ inline void store1(unsigned short* p, float v){ *p = f2bf(v); }

#define GLDS(gp, lp) __builtin_amdgcn_global_load_lds( \
    (const __attribute__((address_space(1))) void*)(gp), \
    (__attribute__((address_space(3))) void*)(lp), 16, 0, 0)

#define WAITV(N) asm volatile("s_waitcnt vmcnt(" #N ")" ::: "memory")

// ============================================================================
// 256x256 8-phase GEMM (T1 XCD-swizzle + T2 LDS XOR-swizzle + T3/T4 counted
// vmcnt + T5 setprio). C[m,n] = scale*(sum_k A[m,k]*B[n,k]) + epilogue.
// A:[M,K] rm, B:[N,K] rm. M,N mult of 256, K mult of 64. 512 threads, 8 waves
// (2 row-groups x 4 col-groups), per-wave output 128x64. LDS 128 KiB.
// Ledger (steady state, per K-tile, 8 gloads issued 1 tile ahead):
//   issue order: p0:{b0,b1} p1:{b2,b3} p2:{a0,a2} p3:{a1,a3}
//   waits: p1 vmcnt(4) [drains a1,a3 of cur tile]  p3 vmcnt(2) [drains
//   b*,a0,a2 of next tile]. Consuming ds_reads are always after a barrier
//   that follows the covering vmcnt in all waves.
// ============================================================================
template<typename OutT, int EPI>
__global__ __launch_bounds__(512, 2)
void gemm256(const unsigned short* __restrict__ Ag,
             const unsigned short* __restrict__ Bg,
             OutT* __restrict__ Cg,
             int K, int lda, int ldb, int ldc,
             long sA, long sB, long sC,
             const float* __restrict__ bias,
             const float* __restrict__ resid, long sR,
             float scale)
{
    // bijective XCD-chunked remap (grid product divisible by 8)
    const int gx = gridDim.x, gy = gridDim.y;
    const int nwg  = gx * gy * (int)gridDim.z;
    const int orig = blockIdx.x + gx * (blockIdx.y + gy * blockIdx.z);
    const int cpx  = nwg >> 3;
    const int nid  = (orig & 7) * cpx + (orig >> 3);
    const int bx   = nid % gx;
    const int tmp  = nid / gx;
    const int by   = tmp % gy;
    const int bz   = tmp / gy;

    Ag += (long)bz * sA;
    Bg += (long)bz * sB;
    Cg += (long)bz * sC;
    const int m0 = by * 256;
    const int n0 = bx * 256;

    __shared__ unsigned short As[2][16384];  // 2 x 256rows x 64 = 2 x 32 KB
    __shared__ unsigned short Bs[2][16384];  // 2 x 32 KB   (total 128 KB)

    const int t    = threadIdx.x;
    const int wave = t >> 6;
    const int lane = t & 63;
    const int rg   = wave >> 2;        // 0..1 row group
    const int cg   = wave & 3;         // 0..3 col group
    const int wm   = rg * 128;
    const int wn   = cg * 64;
    const int lhi  = lane >> 4;
    const int llo  = lane & 15;

    f32x4 acc[4][8];
#pragma unroll
    for (int p = 0; p < 4; p++)
#pragma unroll
        for (int f = 0; f < 8; f++) acc[p][f] = (f32x4)(0.0f);

    // chunk = 64 rows x 64 cols bf16 = 8 KB = one gload per thread (16 B).
    // LDS linear: thread t -> shorts [t*8 .. t*8+7] of the chunk (row t>>3,
    // 16B-slot t&7). Global source slot XOR-swizzled: cs = cb ^ (row&7).
    const int s_rr = t >> 3, s_cb = t & 7;
    const int s_cs = s_cb ^ (s_rr & 7);
    auto stageA = [&](int bi, int k0, int j){
        GLDS(Ag + (long)(m0 + j * 64 + s_rr) * lda + k0 + s_cs * 8,
             &As[bi][j * 4096 + wave * 512]);
    };
    auto stageB = [&](int bi, int k0, int j){
        GLDS(Bg + (long)(n0 + j * 64 + s_rr) * ldb + k0 + s_cs * 8,
             &Bs[bi][j * 4096 + wave * 512]);
    };

    const int nt = K >> 6;
    // prologue: tile 0, exact steady-state issue order
    stageB(0, 0, 0); stageB(0, 0, 1); stageB(0, 0, 2); stageB(0, 0, 3);
    stageA(0, 0, 0); stageA(0, 0, 2); stageA(0, 0, 1); stageA(0, 0, 3);
    WAITV(2);                       // b0..b3,a0,a2 landed; a1,a3 in flight
    __builtin_amdgcn_s_barrier();
    __builtin_amdgcn_sched_barrier(0);

    int cur = 0;
    for (int kt = 0; kt < nt; kt++){
        const bool more = (kt + 1 < nt);
        const int nk0 = (kt + 1) << 6;
#pragma unroll
        for (int p = 0; p < 4; p++){
            const int h = p >> 1, cl = p & 1;
            // --- ds-read this phase's fragments (data guaranteed landed) ---
            short8 af[2][4], bf[2][2];
#pragma unroll
            for (int ks = 0; ks < 2; ks++){
#pragma unroll
                for (int mi = 0; mi < 4; mi++){
                    const int r  = wm + h * 64 + mi * 16 + llo;
                    const int pc = (ks * 4 + lhi) ^ (r & 7);
                    af[ks][mi] = *(const short8*)(&As[cur][r * 64 + pc * 8]);
                }
#pragma unroll
                for (int ni = 0; ni < 2; ni++){
                    const int r  = wn + cl * 32 + ni * 16 + llo;
                    const int pc = (ks * 4 + lhi) ^ (r & 7);
                    bf[ks][ni] = *(const short8*)(&Bs[cur][r * 64 + pc * 8]);
                }
            }
            __builtin_amdgcn_sched_barrier(0);
            // --- stage 2 chunks of next tile ---
            if (more){
                if (p == 0){ stageB(cur ^ 1, nk0, 0); stageB(cur ^ 1, nk0, 1); }
                if (p == 1){ stageB(cur ^ 1, nk0, 2); stageB(cur ^ 1, nk0, 3); }
                if (p == 2){ stageA(cur ^ 1, nk0, 0); stageA(cur ^ 1, nk0, 2); }
                if (p == 3){ stageA(cur ^ 1, nk0, 1); stageA(cur ^ 1, nk0, 3); }
            }
            // --- counted waits (ledger) ---
            if (p == 1){ if (more) WAITV(4); else WAITV(0); }
            if (p == 3){ if (more) WAITV(2); }
            __builtin_amdgcn_s_barrier();
            __builtin_amdgcn_sched_barrier(0);
            // --- MFMA cluster (compiler inserts lgkmcnt for af/bf deps) ---
            __builtin_amdgcn_s_setprio(1);
#pragma unroll
            for (int ks = 0; ks < 2; ks++)
#pragma unroll
                for (int mi = 0; mi < 4; mi++)
#pragma unroll
                    for (int ni = 0; ni < 2; ni++)
                        acc[p][mi * 2 + ni] = __builtin_amdgcn_mfma_f32_16x16x32_bf16(
                            af[ks][mi], bf[ks][ni], acc[p][mi * 2 + ni], 0, 0, 0);
            __builtin_amdgcn_s_setprio(0);
            __builtin_amdgcn_s_barrier();
            __builtin_amdgcn_sched_barrier(0);
        }
        cur ^= 1;
    }

    // epilogue. D frag layout: col = lane&15, row = (lane>>4)*4 + reg [m89]
#pragma unroll
    for (int p = 0; p < 4; p++){
        const int h = p >> 1, cl = p & 1;
#pragma unroll
        for (int mi = 0; mi < 4; mi++){
#pragma unroll
            for (int ni = 0; ni < 2; ni++){
                const int n  = n0 + wn + cl * 32 + ni * 16 + llo;
                const int mb = m0 + wm + h * 64 + mi * 16 + lhi * 4;
                f32x4 v = acc[p][mi * 2 + ni];
#pragma unroll
                for (int j = 0; j < 4; j++){
                    const int m = mb + j;
                    float val = v[j] * scale;
                    if (EPI == 1) val += bias[n];
                    if (EPI == 2) val += bias[m];
                    if (EPI == 3) val += bias[m] + resid[(long)bz * sR + (long)m * ldc + n];
                    store1(&Cg[(long)m * ldc + n], val);
                }
            }
        }
    }
}

// ============================================================================
// 128x128 2-phase GEMM (round-3 kernel, kept for the K=512 small GEMMs)
// ============================================================================
template<typename OutT, int EPI>
__global__ __launch_bounds__(256)
void gemm_nt(const unsigned short* __restrict__ Ag,
             const unsigned short* __restrict__ Bg,
             OutT* __restrict__ Cg,
             int K, int lda, int ldb, int ldc,
             long sA, long sB, long sC,
             const float* __restrict__ bias,
             const float* __restrict__ resid, long sR,
             float scale)
{
    const int gx = gridDim.x, gy = gridDim.y;
    const int nwg  = gx * gy * (int)gridDim.z;
    const int orig = blockIdx.x + gx * (blockIdx.y + gy * blockIdx.z);
    const int cpx  = nwg >> 3;
    const int nid  = (orig & 7) * cpx + (orig >> 3);
    const int bx   = nid % gx;
    const int tmp  = nid / gx;
    const int by   = tmp % gy;
    const int bz   = tmp / gy;

    Ag += (long)bz * sA;
    Bg += (long)bz * sB;
    Cg += (long)bz * sC;
    const int m0 = by * 128;
    const int n0 = bx * 128;

    __shared__ unsigned short As[2][128 * 64];
    __shared__ unsigned short Bs[2][128 * 64];

    const int t    = threadIdx.x;
    const int wave = t >> 6;
    const int lane = t & 63;
    const int wm   = (wave >> 1) << 6;
    const int wn   = (wave & 1) << 6;
    const int lhi  = lane >> 4;
    const int llo  = lane & 15;

    f32x4 acc[4][4];
#pragma unroll
    for (int i = 0; i < 4; i++)
#pragma unroll
        for (int j = 0; j < 4; j++) acc[i][j] = (f32x4)(0.0f);

    auto stage = [&](int bi, int k0){
#pragma unroll
        for (int i = 0; i < 4; i++){
            const int tt = i * 256 + t;
            const int r  = tt >> 3;
            const int cb = tt & 7;
            const int cs = cb ^ (r & 7);
            GLDS(Ag + (long)(m0 + r) * lda + k0 + cs * 8, &As[bi][i * 2048 + wave * 512]);
            GLDS(Bg + (long)(n0 + r) * ldb + k0 + cs * 8, &Bs[bi][i * 2048 + wave * 512]);
        }
    };

    const int nt = K >> 6;
    stage(0, 0);
    __syncthreads();

    int cur = 0;
    for (int kt = 0; kt < nt; kt++){
        if (kt + 1 < nt) stage(cur ^ 1, (kt + 1) << 6);
#pragma unroll
        for (int ksub = 0; ksub < 2; ksub++){
            short8 af[4], bf[4];
#pragma unroll
            for (int mi = 0; mi < 4; mi++){
                const int r  = wm + mi * 16 + llo;
                const int cs = (ksub * 4 + lhi) ^ (r & 7);
                af[mi] = *(const short8*)(&As[cur][r * 64 + cs * 8]);
            }
#pragma unroll
            for (int ni = 0; ni < 4; ni++){
                const int r  = wn + ni * 16 + llo;
                const int cs = (ksub * 4 + lhi) ^ (r & 7);
                bf[ni] = *(const short8*)(&Bs[cur][r * 64 + cs * 8]);
            }
#pragma unroll
            for (int mi = 0; mi < 4; mi++)
#pragma unroll
                for (int ni = 0; ni < 4; ni++)
                    acc[mi][ni] = __builtin_amdgcn_mfma_f32_16x16x32_bf16(
                        af[mi], bf[ni], acc[mi][ni], 0, 0, 0);
        }
        __syncthreads();
        cur ^= 1;
    }

#pragma unroll
    for (int mi = 0; mi < 4; mi++){
#pragma unroll
        for (int ni = 0; ni < 4; ni++){
            const int n  = n0 + wn + ni * 16 + llo;
            const int mb = m0 + wm + mi * 16 + lhi * 4;
            f32x4 v = acc[mi][ni];
#pragma unroll
            for (int j = 0; j < 4; j++){
                const int m = mb + j;
                float val = v[j] * scale;
                if (EPI == 1) val += bias[n];
                if (EPI == 2) val += bias[m];
                if (EPI == 3) val += bias[m] + resid[(long)bz * sR + (long)m * ldc + n];
                store1(&Cg[(long)m * ldc + n], val);
            }
        }
    }
}

// ---- GroupNorm: B=8, C=512, L=2048, G=8 -> 64 (b,g) groups ----

__global__ void gn_partial(const float* __restrict__ x, float* __restrict__ part){
    const long base = (long)blockIdx.x * 8192;
    const float4* xp = (const float4*)(x + base);
    float s = 0.f, ss = 0.f;
    for (int i = threadIdx.x; i < 2048; i += 256){
        float4 v = xp[i];
        s  += (v.x + v.y) + (v.z + v.w);
        ss += (v.x * v.x + v.y * v.y) + (v.z * v.z + v.w * v.w);
    }
    for (int o = 32; o; o >>= 1){ s += __shfl_down(s, o); ss += __shfl_down(ss, o); }
    __shared__ float rs[4], rss[4];
    const int wave = threadIdx.x >> 6, lane = threadIdx.x & 63;
    if (lane == 0){ rs[wave] = s; rss[wave] = ss; }
    __syncthreads();
    if (threadIdx.x == 0){
        part[blockIdx.x * 2]     = (rs[0] + rs[1]) + (rs[2] + rs[3]);
        part[blockIdx.x * 2 + 1] = (rss[0] + rss[1]) + (rss[2] + rss[3]);
    }
}

__global__ void gn_final(const float* __restrict__ part, float* __restrict__ stats){
    const int bg = threadIdx.x;
    if (bg >= 64) return;
    float s = 0.f, ss = 0.f;
    for (int c = 0; c < 16; c++){
        s  += part[(bg * 16 + c) * 2];
        ss += part[(bg * 16 + c) * 2 + 1];
    }
    const float inv_n = 1.0f / 131072.0f;
    const float mean = s * inv_n;
    const float var  = ss * inv_n - mean * mean;
    stats[bg * 2]     = mean;
    stats[bg * 2 + 1] = rsqrtf(var + 1e-6f);
}

__global__ void norm_transpose(const float* __restrict__ x, const float* __restrict__ stats,
                               const float* __restrict__ gamma, const float* __restrict__ beta,
                               unsigned short* __restrict__ ht){
    const int b = blockIdx.z, c0 = blockIdx.y * 64, l0 = blockIdx.x * 64;
    const int bg = b * 8 + (c0 >> 6);
    const float mean = stats[bg * 2], rstd = stats[bg * 2 + 1];
    __shared__ unsigned short tile[64][66];
    const float* xb = x + (long)b * 1048576;
    const int t = threadIdx.x;
#pragma unroll
    for (int i = 0; i < 16; i++){
        const int idx = i * 256 + t;
        const int c = idx >> 6, l = idx & 63;
        float v = xb[(long)(c0 + c) * 2048 + l0 + l];
        v = (v - mean) * rstd * gamma[c0 + c] + beta[c0 + c];
        tile[l][c] = f2bf(v);
    }
    __syncthreads();
    unsigned short* htb = ht + (long)b * 1048576;
#pragma unroll
    for (int i = 0; i < 16; i++){
        const int idx = i * 256 + t;
        const int l = idx >> 6, c = idx & 63;
        htb[(long)(l0 + l) * 512 + c0 + c] = tile[l][c];
    }
}

__global__ void weights_to_bf16(const float4* __restrict__ wq, const float4* __restrict__ wk,
                                const float4* __restrict__ wv, const float4* __restrict__ wo,
                                ushort4v* __restrict__ out){
    const int i = blockIdx.x * 256 + threadIdx.x;
    const int w = i >> 16, off = i & 65535;
    const float4* src = (w == 0) ? wq : (w == 1) ? wk : (w == 2) ? wv : wo;
    float4 v = src[off];
    ushort4v o;
    o.x = f2bf(v.x); o.y = f2bf(v.y); o.z = f2bf(v.z); o.w = f2bf(v.w);
    out[i] = o;
}

__global__ void softmax_inplace(unsigned short* __restrict__ p){
    const long base = (long)blockIdx.x * 2048;
    ushort8* pp = (ushort8*)(p + base);
    const int t = threadIdx.x;
    ushort8 v = pp[t];
    float f[8];
#pragma unroll
    for (int j = 0; j < 8; j++) f[j] = bf2f(v[j]);
    float mx = f[0];
#pragma unroll
    for (int j = 1; j < 8; j++) mx = fmaxf(mx, f[j]);
    for (int o = 32; o; o >>= 1) mx = fmaxf(mx, __shfl_xor(mx, o));
    __shared__ float rmax[4], rsum[4];
    const int wave = t >> 6, lane = t & 63;
    if (lane == 0) rmax[wave] = mx;
    __syncthreads();
    mx = fmaxf(fmaxf(rmax[0], rmax[1]), fmaxf(rmax[2], rmax[3]));
    float sum = 0.f;
#pragma unroll
    for (int j = 0; j < 8; j++){ f[j] = __expf(f[j] - mx); sum += f[j]; }
    for (int o = 32; o; o >>= 1) sum += __shfl_xor(sum, o);
    if (lane == 0) rsum[wave] = sum;
    __syncthreads();
    sum = (rsum[0] + rsum[1]) + (rsum[2] + rsum[3]);
    const float inv = 1.0f / sum;
    ushort8 o8;
#pragma unroll
    for (int j = 0; j < 8; j++) o8[j] = f2bf(f[j] * inv);
    pp[t] = o8;
}

// ---- workspace layout (bytes) ----
enum : long {
    OFF_WQ  = 0,
    OFF_WK  = 524288,
    OFF_WV  = 1048576,
    OFF_WO  = 1572864,
    OFF_HT  = 2097152,              // [B][L][C] bf16
    OFF_QT  = OFF_HT  + 16777216,   // [B][L][C] bf16
    OFF_KT  = OFF_QT  + 16777216,   // [B][L][C] bf16
    OFF_V   = OFF_KT  + 16777216,   // [B][C][L] bf16
    OFF_H2  = OFF_V   + 16777216,   // [B][L][C] bf16
    OFF_P   = OFF_H2  + 16777216,   // [B][L][L] bf16 (S here, softmax in-place)
    OFF_GNP = OFF_P   + 67108864,
    OFF_GNS = OFF_GNP + 8192,
    OFF_END = OFF_GNS + 512
};

extern "C" void kernel_launch(void* const* d_in, const int* in_sizes, int n_in,
                              void* d_out, int out_size, void* d_ws, size_t ws_size,
                              hipStream_t stream)
{
    const float* x     = (const float*)d_in[0];
    const float* gamma = (const float*)d_in[1];
    const float* beta  = (const float*)d_in[2];
    const float* wq    = (const float*)d_in[3];
    const float* bq    = (const float*)d_in[4];
    const float* wk    = (const float*)d_in[5];
    const float* bk    = (const float*)d_in[6];
    const float* wv    = (const float*)d_in[7];
    const float* bv    = (const float*)d_in[8];
    const float* wo    = (const float*)d_in[9];
    const float* bo    = (const float*)d_in[10];
    float* out = (float*)d_out;
    char* ws = (char*)d_ws;

    if (ws_size < (size_t)OFF_END){
        fprintf(stderr, "kernel_launch: ws too small (%zu < %ld)\n", ws_size, (long)OFF_END);
        return;
    }

    unsigned short* HT  = (unsigned short*)(ws + OFF_HT);
    unsigned short* QT  = (unsigned short*)(ws + OFF_QT);
    unsigned short* KT  = (unsigned short*)(ws + OFF_KT);
    unsigned short* V   = (unsigned short*)(ws + OFF_V);
    unsigned short* H2  = (unsigned short*)(ws + OFF_H2);
    unsigned short* P   = (unsigned short*)(ws + OFF_P);
    float*          GNP = (float*)(ws + OFF_GNP);
    float*          GNS = (float*)(ws + OFF_GNS);
    unsigned short* WQb = (unsigned short*)(ws + OFF_WQ);
    unsigned short* WKb = (unsigned short*)(ws + OFF_WK);
    unsigned short* WVb = (unsigned short*)(ws + OFF_WV);
    unsigned short* WOb = (unsigned short*)(ws + OFF_WO);

    const long LC = 1048576;   // 2048*512
    const long LL = 4194304;   // 2048*2048

    weights_to_bf16<<<1024, 256, 0, stream>>>(
        (const float4*)wq, (const float4*)wk, (const float4*)wv, (const float4*)wo,
        (ushort4v*)(ws + OFF_WQ));

    gn_partial<<<1024, 256, 0, stream>>>(x, GNP);
    gn_final<<<1, 64, 0, stream>>>(GNP, GNS);
    norm_transpose<<<dim3(32, 8, 8), 256, 0, stream>>>(x, GNS, gamma, beta, HT);

    // q_t[l,o] / k_t[l,o]  (M=2048,N=512,K=512) -- 2-phase 128^2
    gemm_nt<unsigned short, 1><<<dim3(4, 16, 8), 256, 0, stream>>>(
        HT, WQb, QT, 512, 512, 512, 512, LC, 0, LC, bq, nullptr, 0, 1.0f);
    gemm_nt<unsigned short, 1><<<dim3(4, 16, 8), 256, 0, stream>>>(
        HT, WKb, KT, 512, 512, 512, 512, LC, 0, LC, bk, nullptr, 0, 1.0f);
    // v[o,l]  (M=512,N=2048,K=512)
    gemm_nt<unsigned short, 2><<<dim3(16, 4, 8), 256, 0, stream>>>(
        WVb, HT, V, 512, 512, 512, 2048, 0, LC, LC, bv, nullptr, 0, 1.0f);

    // scores -> P bf16 (M=N=2048,K=512) -- 8-phase 256^2, batch-per-XCD
    gemm256<unsigned short, 0><<<dim3(8, 8, 8), 512, 0, stream>>>(
        QT, KT, P, 512, 512, 512, 2048, LC, LC, LL, nullptr, nullptr, 0, 0.04419417382f);

    softmax_inplace<<<16384, 256, 0, stream>>>(P);

    // h2_t[i,c] = sum_j p[i,j] v[c,j]  (M=2048,N=512,K=2048) -- 8-phase 256^2
    gemm256<unsigned short, 0><<<dim3(2, 8, 8), 512, 0, stream>>>(
        P, V, H2, 2048, 2048, 2048, 512, LL, LC, LC, nullptr, nullptr, 0, 1.0f);

    // out[o,l] = sum_c wo[o,c] h2_t[l,c] + bo[o] + x[o,l]  (M=512,N=2048,K=512)
    gemm_nt<float, 3><<<dim3(16, 4, 8), 256, 0, stream>>>(
        WOb, H2, out, 512, 512, 512, 2048, 0, LC, LC, bo, x, LC, 1.0f);
}

// Round 6
// 276.867 us; speedup vs baseline: 1.1162x; 1.1162x over previous
//
#include <hip/hip_runtime.h>
#include <hip/hip_bf16.h>
#include <cstdio>

typedef __attribute__((ext_vector_type(8))) short short8;
typedef __attribute__((ext_vector_type(8))) unsigned short ushort8;
typedef __attribute__((ext_vector_type(4))) float f32x4;
typedef __attribute__((ext_vector_type(4))) unsigned short ushort4v;

__device__ inline unsigned short f2bf(float f){
    unsigned int u = __float_as_uint(f);
    unsigned int r = (u + 0x7fffu + ((u >> 16) & 1u)) >> 16;
    return (unsigned short)r;
}
__device__ inline float bf2f(unsigned short b){
    return __uint_as_float((unsigned int)b << 16);
}

__device__ inline void store1(float* p, float v){ *p = v; }
__device__ inline void store1(unsigned short* p, float v){ *p = f2bf(v); }

#define GLDS(gp, lp) __builtin_amdgcn_global_load_lds( \
    (const __attribute__((address_space(1))) void*)(gp), \
    (__attribute__((address_space(3))) void*)(lp), 16, 0, 0)

#define WAITV(N) asm volatile("s_waitcnt vmcnt(" #N ")" ::: "memory")

#define MFMA_Q(ACC, AF, BF) \
    _Pragma("unroll") \
    for (int ks = 0; ks < 2; ks++) \
        _Pragma("unroll") \
        for (int mi = 0; mi < 4; mi++) \
            _Pragma("unroll") \
            for (int ni = 0; ni < 2; ni++) \
                ACC[mi * 2 + ni] = __builtin_amdgcn_mfma_f32_16x16x32_bf16( \
                    AF[ks][mi], BF[ks][ni], ACC[mi * 2 + ni], 0, 0, 0);

// ============================================================================
// 256x256 8-phase GEMM, fragment-reuse schedule (24 ds_read_b128/wave/K-tile).
// Quadrant order per K-tile: q0=(h0,c0) q1=(h0,c1) q2=(h1,c1) q3=(h1,c0).
//   p0: read af(h0)+bf0; stage nb0,nb1;            barrier; MFMA q0
//   p1: read bf1;        stage nb2,nb3; vmcnt(4);  barrier; MFMA q1   (af reuse)
//   p2: read af(h1);     stage na0,na2;            barrier; MFMA q2   (bf1 reuse)
//   p3: (no reads)       stage na1,na3; vmcnt(2);  barrier; MFMA q3   (bf0 reuse)
// Ledger: a1,a3 (cur) drained by p1's vmcnt(4) before p2 reads them; p3's
// vmcnt(2) leaves only na1,na3 in flight, which next p0 does not touch.
// ============================================================================
template<typename OutT, int EPI>
__global__ __launch_bounds__(512, 2)
void gemm256(const unsigned short* __restrict__ Ag,
             const unsigned short* __restrict__ Bg,
             OutT* __restrict__ Cg,
             int K, int lda, int ldb, int ldc,
             long sA, long sB, long sC,
             const float* __restrict__ bias,
             const float* __restrict__ resid, long sR,
             float scale)
{
    const int gx = gridDim.x, gy = gridDim.y;
    const int nwg  = gx * gy * (int)gridDim.z;
    const int orig = blockIdx.x + gx * (blockIdx.y + gy * blockIdx.z);
    const int cpx  = nwg >> 3;
    const int nid  = (orig & 7) * cpx + (orig >> 3);
    const int bx   = nid % gx;
    const int tmp  = nid / gx;
    const int by   = tmp % gy;
    const int bz   = tmp / gy;

    Ag += (long)bz * sA;
    Bg += (long)bz * sB;
    Cg += (long)bz * sC;
    const int m0 = by * 256;
    const int n0 = bx * 256;

    __shared__ unsigned short As[2][16384];  // 2 x 32 KB
    __shared__ unsigned short Bs[2][16384];  // 2 x 32 KB (128 KB total)

    const int t    = threadIdx.x;
    const int wave = t >> 6;
    const int lane = t & 63;
    const int rg   = wave >> 2;
    const int cg   = wave & 3;
    const int wm   = rg * 128;
    const int wn   = cg * 64;
    const int lhi  = lane >> 4;
    const int llo  = lane & 15;

    f32x4 acc0[8], acc1[8], acc2[8], acc3[8];
#pragma unroll
    for (int f = 0; f < 8; f++){
        acc0[f] = (f32x4)(0.0f); acc1[f] = (f32x4)(0.0f);
        acc2[f] = (f32x4)(0.0f); acc3[f] = (f32x4)(0.0f);
    }

    // chunk = 64 rows x 64 cols bf16; one 16B gload per thread; LDS linear,
    // global source 16B-slot XOR-swizzled (both-sides rule #21).
    const int s_rr = t >> 3, s_cb = t & 7;
    const int s_cs = s_cb ^ (s_rr & 7);
    auto stageA = [&](int bi, int k0, int j){
        GLDS(Ag + (long)(m0 + j * 64 + s_rr) * lda + k0 + s_cs * 8,
             &As[bi][j * 4096 + wave * 512]);
    };
    auto stageB = [&](int bi, int k0, int j){
        GLDS(Bg + (long)(n0 + j * 64 + s_rr) * ldb + k0 + s_cs * 8,
             &Bs[bi][j * 4096 + wave * 512]);
    };

    const int nt = K >> 6;
    stageB(0, 0, 0); stageB(0, 0, 1); stageB(0, 0, 2); stageB(0, 0, 3);
    stageA(0, 0, 0); stageA(0, 0, 2); stageA(0, 0, 1); stageA(0, 0, 3);
    WAITV(2);                       // b0..b3,a0,a2 landed; a1,a3 in flight
    __builtin_amdgcn_s_barrier();
    __builtin_amdgcn_sched_barrier(0);

    int cur = 0;
    for (int kt = 0; kt < nt; kt++){
        const bool more = (kt + 1 < nt);
        const int nk0 = (kt + 1) << 6;
        short8 af[2][4], bf0[2][2], bf1[2][2];

        // ---------- phase 0: af(h0) + bf0 ; MFMA q0 ----------
#pragma unroll
        for (int ks = 0; ks < 2; ks++){
#pragma unroll
            for (int mi = 0; mi < 4; mi++){
                const int r  = wm + mi * 16 + llo;
                const int pc = (ks * 4 + lhi) ^ (r & 7);
                af[ks][mi] = *(const short8*)(&As[cur][r * 64 + pc * 8]);
            }
#pragma unroll
            for (int ni = 0; ni < 2; ni++){
                const int r  = wn + ni * 16 + llo;
                const int pc = (ks * 4 + lhi) ^ (r & 7);
                bf0[ks][ni] = *(const short8*)(&Bs[cur][r * 64 + pc * 8]);
            }
        }
        __builtin_amdgcn_sched_barrier(0);
        if (more){ stageB(cur ^ 1, nk0, 0); stageB(cur ^ 1, nk0, 1); }
        __builtin_amdgcn_s_barrier();
        __builtin_amdgcn_sched_barrier(0);
        __builtin_amdgcn_s_setprio(1);
        MFMA_Q(acc0, af, bf0);
        __builtin_amdgcn_s_setprio(0);
        __builtin_amdgcn_s_barrier();
        __builtin_amdgcn_sched_barrier(0);

        // ---------- phase 1: bf1 ; MFMA q1 (af reused) ----------
#pragma unroll
        for (int ks = 0; ks < 2; ks++)
#pragma unroll
            for (int ni = 0; ni < 2; ni++){
                const int r  = wn + 32 + ni * 16 + llo;
                const int pc = (ks * 4 + lhi) ^ (r & 7);
                bf1[ks][ni] = *(const short8*)(&Bs[cur][r * 64 + pc * 8]);
            }
        __builtin_amdgcn_sched_barrier(0);
        if (more){ stageB(cur ^ 1, nk0, 2); stageB(cur ^ 1, nk0, 3); WAITV(4); }
        else     { WAITV(0); }
        __builtin_amdgcn_s_barrier();
        __builtin_amdgcn_sched_barrier(0);
        __builtin_amdgcn_s_setprio(1);
        MFMA_Q(acc1, af, bf1);
        __builtin_amdgcn_s_setprio(0);
        __builtin_amdgcn_s_barrier();
        __builtin_amdgcn_sched_barrier(0);

        // ---------- phase 2: af(h1) ; MFMA q2 (bf1 reused) ----------
#pragma unroll
        for (int ks = 0; ks < 2; ks++)
#pragma unroll
            for (int mi = 0; mi < 4; mi++){
                const int r  = wm + 64 + mi * 16 + llo;
                const int pc = (ks * 4 + lhi) ^ (r & 7);
                af[ks][mi] = *(const short8*)(&As[cur][r * 64 + pc * 8]);
            }
        __builtin_amdgcn_sched_barrier(0);
        if (more){ stageA(cur ^ 1, nk0, 0); stageA(cur ^ 1, nk0, 2); }
        __builtin_amdgcn_s_barrier();
        __builtin_amdgcn_sched_barrier(0);
        __builtin_amdgcn_s_setprio(1);
        MFMA_Q(acc2, af, bf1);
        __builtin_amdgcn_s_setprio(0);
        __builtin_amdgcn_s_barrier();
        __builtin_amdgcn_sched_barrier(0);

        // ---------- phase 3: no reads ; MFMA q3 (af h1 + bf0 reused) ----------
        if (more){ stageA(cur ^ 1, nk0, 1); stageA(cur ^ 1, nk0, 3); WAITV(2); }
        __builtin_amdgcn_s_barrier();
        __builtin_amdgcn_sched_barrier(0);
        __builtin_amdgcn_s_setprio(1);
        MFMA_Q(acc3, af, bf0);
        __builtin_amdgcn_s_setprio(0);
        __builtin_amdgcn_s_barrier();
        __builtin_amdgcn_sched_barrier(0);

        cur ^= 1;
    }

    // epilogue. D frag layout: col = lane&15, row = (lane>>4)*4 + reg [m89]
    auto epi = [&](f32x4 (&A)[8], int h, int cl){
#pragma unroll
        for (int mi = 0; mi < 4; mi++){
#pragma unroll
            for (int ni = 0; ni < 2; ni++){
                const int n  = n0 + wn + cl * 32 + ni * 16 + llo;
                const int mb = m0 + wm + h * 64 + mi * 16 + lhi * 4;
                f32x4 v = A[mi * 2 + ni];
#pragma unroll
                for (int j = 0; j < 4; j++){
                    const int m = mb + j;
                    float val = v[j] * scale;
                    if (EPI == 1) val += bias[n];
                    if (EPI == 2) val += bias[m];
                    if (EPI == 3) val += bias[m] + resid[(long)bz * sR + (long)m * ldc + n];
                    store1(&Cg[(long)m * ldc + n], val);
                }
            }
        }
    };
    epi(acc0, 0, 0); epi(acc1, 0, 1); epi(acc2, 1, 1); epi(acc3, 1, 0);
}

// ============================================================================
// 128x128 2-phase GEMM (proven; used for all K=512 GEMMs and PV)
// ============================================================================
template<typename OutT, int EPI>
__global__ __launch_bounds__(256)
void gemm_nt(const unsigned short* __restrict__ Ag,
             const unsigned short* __restrict__ Bg,
             OutT* __restrict__ Cg,
             int K, int lda, int ldb, int ldc,
             long sA, long sB, long sC,
             const float* __restrict__ bias,
             const float* __restrict__ resid, long sR,
             float scale)
{
    const int gx = gridDim.x, gy = gridDim.y;
    const int nwg  = gx * gy * (int)gridDim.z;
    const int orig = blockIdx.x + gx * (blockIdx.y + gy * blockIdx.z);
    const int cpx  = nwg >> 3;
    const int nid  = (orig & 7) * cpx + (orig >> 3);
    const int bx   = nid % gx;
    const int tmp  = nid / gx;
    const int by   = tmp % gy;
    const int bz   = tmp / gy;

    Ag += (long)bz * sA;
    Bg += (long)bz * sB;
    Cg += (long)bz * sC;
    const int m0 = by * 128;
    const int n0 = bx * 128;

    __shared__ unsigned short As[2][128 * 64];
    __shared__ unsigned short Bs[2][128 * 64];

    const int t    = threadIdx.x;
    const int wave = t >> 6;
    const int lane = t & 63;
    const int wm   = (wave >> 1) << 6;
    const int wn   = (wave & 1) << 6;
    const int lhi  = lane >> 4;
    const int llo  = lane & 15;

    f32x4 acc[4][4];
#pragma unroll
    for (int i = 0; i < 4; i++)
#pragma unroll
        for (int j = 0; j < 4; j++) acc[i][j] = (f32x4)(0.0f);

    auto stage = [&](int bi, int k0){
#pragma unroll
        for (int i = 0; i < 4; i++){
            const int tt = i * 256 + t;
            const int r  = tt >> 3;
            const int cb = tt & 7;
            const int cs = cb ^ (r & 7);
            GLDS(Ag + (long)(m0 + r) * lda + k0 + cs * 8, &As[bi][i * 2048 + wave * 512]);
            GLDS(Bg + (long)(n0 + r) * ldb + k0 + cs * 8, &Bs[bi][i * 2048 + wave * 512]);
        }
    };

    const int nt = K >> 6;
    stage(0, 0);
    __syncthreads();

    int cur = 0;
    for (int kt = 0; kt < nt; kt++){
        if (kt + 1 < nt) stage(cur ^ 1, (kt + 1) << 6);
#pragma unroll
        for (int ksub = 0; ksub < 2; ksub++){
            short8 af[4], bf[4];
#pragma unroll
            for (int mi = 0; mi < 4; mi++){
                const int r  = wm + mi * 16 + llo;
                const int cs = (ksub * 4 + lhi) ^ (r & 7);
                af[mi] = *(const short8*)(&As[cur][r * 64 + cs * 8]);
            }
#pragma unroll
            for (int ni = 0; ni < 4; ni++){
                const int r  = wn + ni * 16 + llo;
                const int cs = (ksub * 4 + lhi) ^ (r & 7);
                bf[ni] = *(const short8*)(&Bs[cur][r * 64 + cs * 8]);
            }
#pragma unroll
            for (int mi = 0; mi < 4; mi++)
#pragma unroll
                for (int ni = 0; ni < 4; ni++)
                    acc[mi][ni] = __builtin_amdgcn_mfma_f32_16x16x32_bf16(
                        af[mi], bf[ni], acc[mi][ni], 0, 0, 0);
        }
        __syncthreads();
        cur ^= 1;
    }

#pragma unroll
    for (int mi = 0; mi < 4; mi++){
#pragma unroll
        for (int ni = 0; ni < 4; ni++){
            const int n  = n0 + wn + ni * 16 + llo;
            const int mb = m0 + wm + mi * 16 + lhi * 4;
            f32x4 v = acc[mi][ni];
#pragma unroll
            for (int j = 0; j < 4; j++){
                const int m = mb + j;
                float val = v[j] * scale;
                if (EPI == 1) val += bias[n];
                if (EPI == 2) val += bias[m];
                if (EPI == 3) val += bias[m] + resid[(long)bz * sR + (long)m * ldc + n];
                store1(&Cg[(long)m * ldc + n], val);
            }
        }
    }
}

// ---- GroupNorm: B=8, C=512, L=2048, G=8 -> 64 (b,g) groups ----

__global__ void gn_partial(const float* __restrict__ x, float* __restrict__ part){
    const long base = (long)blockIdx.x * 8192;
    const float4* xp = (const float4*)(x + base);
    float s = 0.f, ss = 0.f;
    for (int i = threadIdx.x; i < 2048; i += 256){
        float4 v = xp[i];
        s  += (v.x + v.y) + (v.z + v.w);
        ss += (v.x * v.x + v.y * v.y) + (v.z * v.z + v.w * v.w);
    }
    for (int o = 32; o; o >>= 1){ s += __shfl_down(s, o); ss += __shfl_down(ss, o); }
    __shared__ float rs[4], rss[4];
    const int wave = threadIdx.x >> 6, lane = threadIdx.x & 63;
    if (lane == 0){ rs[wave] = s; rss[wave] = ss; }
    __syncthreads();
    if (threadIdx.x == 0){
        part[blockIdx.x * 2]     = (rs[0] + rs[1]) + (rs[2] + rs[3]);
        part[blockIdx.x * 2 + 1] = (rss[0] + rss[1]) + (rss[2] + rss[3]);
    }
}

__global__ void gn_final(const float* __restrict__ part, float* __restrict__ stats){
    const int bg = threadIdx.x;
    if (bg >= 64) return;
    float s = 0.f, ss = 0.f;
    for (int c = 0; c < 16; c++){
        s  += part[(bg * 16 + c) * 2];
        ss += part[(bg * 16 + c) * 2 + 1];
    }
    const float inv_n = 1.0f / 131072.0f;
    const float mean = s * inv_n;
    const float var  = ss * inv_n - mean * mean;
    stats[bg * 2]     = mean;
    stats[bg * 2 + 1] = rsqrtf(var + 1e-6f);
}

__global__ void norm_transpose(const float* __restrict__ x, const float* __restrict__ stats,
                               const float* __restrict__ gamma, const float* __restrict__ beta,
                               unsigned short* __restrict__ ht){
    const int b = blockIdx.z, c0 = blockIdx.y * 64, l0 = blockIdx.x * 64;
    const int bg = b * 8 + (c0 >> 6);
    const float mean = stats[bg * 2], rstd = stats[bg * 2 + 1];
    __shared__ unsigned short tile[64][66];
    const float* xb = x + (long)b * 1048576;
    const int t = threadIdx.x;
#pragma unroll
    for (int i = 0; i < 16; i++){
        const int idx = i * 256 + t;
        const int c = idx >> 6, l = idx & 63;
        float v = xb[(long)(c0 + c) * 2048 + l0 + l];
        v = (v - mean) * rstd * gamma[c0 + c] + beta[c0 + c];
        tile[l][c] = f2bf(v);
    }
    __syncthreads();
    unsigned short* htb = ht + (long)b * 1048576;
#pragma unroll
    for (int i = 0; i < 16; i++){
        const int idx = i * 256 + t;
        const int l = idx >> 6, c = idx & 63;
        htb[(long)(l0 + l) * 512 + c0 + c] = tile[l][c];
    }
}

__global__ void weights_to_bf16(const float4* __restrict__ wq, const float4* __restrict__ wk,
                                const float4* __restrict__ wv, const float4* __restrict__ wo,
                                ushort4v* __restrict__ out){
    const int i = blockIdx.x * 256 + threadIdx.x;
    const int w = i >> 16, off = i & 65535;
    const float4* src = (w == 0) ? wq : (w == 1) ? wk : (w == 2) ? wv : wo;
    float4 v = src[off];
    ushort4v o;
    o.x = f2bf(v.x); o.y = f2bf(v.y); o.z = f2bf(v.z); o.w = f2bf(v.w);
    out[i] = o;
}

__global__ void softmax_inplace(unsigned short* __restrict__ p){
    const long base = (long)blockIdx.x * 2048;
    ushort8* pp = (ushort8*)(p + base);
    const int t = threadIdx.x;
    ushort8 v = pp[t];
    float f[8];
#pragma unroll
    for (int j = 0; j < 8; j++) f[j] = bf2f(v[j]);
    float mx = f[0];
#pragma unroll
    for (int j = 1; j < 8; j++) mx = fmaxf(mx, f[j]);
    for (int o = 32; o; o >>= 1) mx = fmaxf(mx, __shfl_xor(mx, o));
    __shared__ float rmax[4], rsum[4];
    const int wave = t >> 6, lane = t & 63;
    if (lane == 0) rmax[wave] = mx;
    __syncthreads();
    mx = fmaxf(fmaxf(rmax[0], rmax[1]), fmaxf(rmax[2], rmax[3]));
    float sum = 0.f;
#pragma unroll
    for (int j = 0; j < 8; j++){ f[j] = __expf(f[j] - mx); sum += f[j]; }
    for (int o = 32; o; o >>= 1) sum += __shfl_xor(sum, o);
    if (lane == 0) rsum[wave] = sum;
    __syncthreads();
    sum = (rsum[0] + rsum[1]) + (rsum[2] + rsum[3]);
    const float inv = 1.0f / sum;
    ushort8 o8;
#pragma unroll
    for (int j = 0; j < 8; j++) o8[j] = f2bf(f[j] * inv);
    pp[t] = o8;
}

// ---- workspace layout (bytes) ----
enum : long {
    OFF_WQ  = 0,
    OFF_WK  = 524288,
    OFF_WV  = 1048576,
    OFF_WO  = 1572864,
    OFF_HT  = 2097152,              // [B][L][C] bf16
    OFF_QT  = OFF_HT  + 16777216,   // [B][L][C] bf16
    OFF_KT  = OFF_QT  + 16777216,   // [B][L][C] bf16
    OFF_V   = OFF_KT  + 16777216,   // [B][C][L] bf16
    OFF_H2  = OFF_V   + 16777216,   // [B][L][C] bf16
    OFF_P   = OFF_H2  + 16777216,   // [B][L][L] bf16 (S here, softmax in-place)
    OFF_GNP = OFF_P   + 67108864,
    OFF_GNS = OFF_GNP + 8192,
    OFF_END = OFF_GNS + 512
};

extern "C" void kernel_launch(void* const* d_in, const int* in_sizes, int n_in,
                              void* d_out, int out_size, void* d_ws, size_t ws_size,
                              hipStream_t stream)
{
    const float* x     = (const float*)d_in[0];
    const float* gamma = (const float*)d_in[1];
    const float* beta  = (const float*)d_in[2];
    const float* wq    = (const float*)d_in[3];
    const float* bq    = (const float*)d_in[4];
    const float* wk    = (const float*)d_in[5];
    const float* bk    = (const float*)d_in[6];
    const float* wv    = (const float*)d_in[7];
    const float* bv    = (const float*)d_in[8];
    const float* wo    = (const float*)d_in[9];
    const float* bo    = (const float*)d_in[10];
    float* out = (float*)d_out;
    char* ws = (char*)d_ws;

    if (ws_size < (size_t)OFF_END){
        fprintf(stderr, "kernel_launch: ws too small (%zu < %ld)\n", ws_size, (long)OFF_END);
        return;
    }

    unsigned short* HT  = (unsigned short*)(ws + OFF_HT);
    unsigned short* QT  = (unsigned short*)(ws + OFF_QT);
    unsigned short* KT  = (unsigned short*)(ws + OFF_KT);
    unsigned short* V   = (unsigned short*)(ws + OFF_V);
    unsigned short* H2  = (unsigned short*)(ws + OFF_H2);
    unsigned short* P   = (unsigned short*)(ws + OFF_P);
    float*          GNP = (float*)(ws + OFF_GNP);
    float*          GNS = (float*)(ws + OFF_GNS);
    unsigned short* WQb = (unsigned short*)(ws + OFF_WQ);
    unsigned short* WKb = (unsigned short*)(ws + OFF_WK);
    unsigned short* WVb = (unsigned short*)(ws + OFF_WV);
    unsigned short* WOb = (unsigned short*)(ws + OFF_WO);

    const long LC = 1048576;   // 2048*512
    const long LL = 4194304;   // 2048*2048

    weights_to_bf16<<<1024, 256, 0, stream>>>(
        (const float4*)wq, (const float4*)wk, (const float4*)wv, (const float4*)wo,
        (ushort4v*)(ws + OFF_WQ));

    gn_partial<<<1024, 256, 0, stream>>>(x, GNP);
    gn_final<<<1, 64, 0, stream>>>(GNP, GNS);
    norm_transpose<<<dim3(32, 8, 8), 256, 0, stream>>>(x, GNS, gamma, beta, HT);

    // q_t[l,o] / k_t[l,o]  (M=2048,N=512,K=512) -- 2-phase 128^2
    gemm_nt<unsigned short, 1><<<dim3(4, 16, 8), 256, 0, stream>>>(
        HT, WQb, QT, 512, 512, 512, 512, LC, 0, LC, bq, nullptr, 0, 1.0f);
    gemm_nt<unsigned short, 1><<<dim3(4, 16, 8), 256, 0, stream>>>(
        HT, WKb, KT, 512, 512, 512, 512, LC, 0, LC, bk, nullptr, 0, 1.0f);
    // v[o,l]  (M=512,N=2048,K=512)
    gemm_nt<unsigned short, 2><<<dim3(16, 4, 8), 256, 0, stream>>>(
        WVb, HT, V, 512, 512, 512, 2048, 0, LC, LC, bv, nullptr, 0, 1.0f);

    // scores -> P bf16 (M=N=2048,K=512) -- fixed 8-phase 256^2, 512 wgs
    gemm256<unsigned short, 0><<<dim3(8, 8, 8), 512, 0, stream>>>(
        QT, KT, P, 512, 512, 512, 2048, LC, LC, LL, nullptr, nullptr, 0, 0.04419417382f);

    softmax_inplace<<<16384, 256, 0, stream>>>(P);

    // h2_t[i,c] = sum_j p[i,j] v[c,j]  (M=2048,N=512,K=2048) -- 2-phase, 512 wgs
    gemm_nt<unsigned short, 0><<<dim3(4, 16, 8), 256, 0, stream>>>(
        P, V, H2, 2048, 2048, 2048, 512, LL, LC, LC, nullptr, nullptr, 0, 1.0f);

    // out[o,l] = sum_c wo[o,c] h2_t[l,c] + bo[o] + x[o,l]  (M=512,N=2048,K=512)
    gemm_nt<float, 3><<<dim3(16, 4, 8), 256, 0, stream>>>(
        WOb, H2, out, 512, 512, 512, 2048, 0, LC, LC, bo, x, LC, 1.0f);
}

// Round 7
// 270.024 us; speedup vs baseline: 1.1445x; 1.0253x over previous
//
#include <hip/hip_runtime.h>
#include <hip/hip_bf16.h>
#include <cstdio>

typedef __attribute__((ext_vector_type(8))) short short8;
typedef __attribute__((ext_vector_type(8))) unsigned short ushort8;
typedef __attribute__((ext_vector_type(4))) float f32x4;
typedef __attribute__((ext_vector_type(4))) unsigned short ushort4v;

__device__ inline unsigned short f2bf(float f){
    unsigned int u = __float_as_uint(f);
    unsigned int r = (u + 0x7fffu + ((u >> 16) & 1u)) >> 16;
    return (unsigned short)r;
}
__device__ inline float bf2f(unsigned short b){
    return __uint_as_float((unsigned int)b << 16);
}

__device__ inline void store1(float* p, float v){ *p = v; }
__device__ inline void store1(unsigned short* p, float v){ *p = f2bf(v); }

#define GLDS(gp, lp) __builtin_amdgcn_global_load_lds( \
    (const __attribute__((address_space(1))) void*)(gp), \
    (__attribute__((address_space(3))) void*)(lp), 16, 0, 0)

#define WAITV(N) asm volatile("s_waitcnt vmcnt(" #N ")" ::: "memory")

#define MFMA_Q(ACC, AF, BF) \
    _Pragma("unroll") \
    for (int ks = 0; ks < 2; ks++) \
        _Pragma("unroll") \
        for (int mi = 0; mi < 4; mi++) \
            _Pragma("unroll") \
            for (int ni = 0; ni < 2; ni++) \
                ACC[mi * 2 + ni] = __builtin_amdgcn_mfma_f32_16x16x32_bf16( \
                    AF[ks][mi], BF[ks][ni], ACC[mi * 2 + ni], 0, 0, 0);

// ============================================================================
// 256x256 8-phase GEMM, fragment-reuse schedule (24 ds_read_b128/wave/K-tile).
// EPI: 0 none; 4 = P-with-exp: store bf16 exp(scale*s) and atomicAdd per-row
// sums of the bf16-rounded values into rs[bz*sRS + m] (softmax denominator).
// Ledger (see round-4 comment): p1 vmcnt(4), p3 vmcnt(2); verified.
// ============================================================================
template<typename OutT, int EPI>
__global__ __launch_bounds__(512, 2)
void gemm256(const unsigned short* __restrict__ Ag,
             const unsigned short* __restrict__ Bg,
             OutT* __restrict__ Cg,
             int K, int lda, int ldb, int ldc,
             long sA, long sB, long sC,
             const float* __restrict__ bias,
             float* __restrict__ rs, long sRS,
             float scale)
{
    const int gx = gridDim.x, gy = gridDim.y;
    const int nwg  = gx * gy * (int)gridDim.z;
    const int orig = blockIdx.x + gx * (blockIdx.y + gy * blockIdx.z);
    const int cpx  = nwg >> 3;
    const int nid  = (orig & 7) * cpx + (orig >> 3);
    const int bx   = nid % gx;
    const int tmp  = nid / gx;
    const int by   = tmp % gy;
    const int bz   = tmp / gy;

    Ag += (long)bz * sA;
    Bg += (long)bz * sB;
    Cg += (long)bz * sC;
    const int m0 = by * 256;
    const int n0 = bx * 256;

    __shared__ unsigned short As[2][16384];  // 2 x 32 KB
    __shared__ unsigned short Bs[2][16384];  // 2 x 32 KB (128 KB total)

    const int t    = threadIdx.x;
    const int wave = t >> 6;
    const int lane = t & 63;
    const int rg   = wave >> 2;
    const int cg   = wave & 3;
    const int wm   = rg * 128;
    const int wn   = cg * 64;
    const int lhi  = lane >> 4;
    const int llo  = lane & 15;

    f32x4 acc0[8], acc1[8], acc2[8], acc3[8];
#pragma unroll
    for (int f = 0; f < 8; f++){
        acc0[f] = (f32x4)(0.0f); acc1[f] = (f32x4)(0.0f);
        acc2[f] = (f32x4)(0.0f); acc3[f] = (f32x4)(0.0f);
    }

    const int s_rr = t >> 3, s_cb = t & 7;
    const int s_cs = s_cb ^ (s_rr & 7);
    auto stageA = [&](int bi, int k0, int j){
        GLDS(Ag + (long)(m0 + j * 64 + s_rr) * lda + k0 + s_cs * 8,
             &As[bi][j * 4096 + wave * 512]);
    };
    auto stageB = [&](int bi, int k0, int j){
        GLDS(Bg + (long)(n0 + j * 64 + s_rr) * ldb + k0 + s_cs * 8,
             &Bs[bi][j * 4096 + wave * 512]);
    };

    const int nt = K >> 6;
    stageB(0, 0, 0); stageB(0, 0, 1); stageB(0, 0, 2); stageB(0, 0, 3);
    stageA(0, 0, 0); stageA(0, 0, 2); stageA(0, 0, 1); stageA(0, 0, 3);
    WAITV(2);
    __builtin_amdgcn_s_barrier();
    __builtin_amdgcn_sched_barrier(0);

    int cur = 0;
    for (int kt = 0; kt < nt; kt++){
        const bool more = (kt + 1 < nt);
        const int nk0 = (kt + 1) << 6;
        short8 af[2][4], bf0[2][2], bf1[2][2];

        // phase 0: af(h0)+bf0 ; MFMA q0
#pragma unroll
        for (int ks = 0; ks < 2; ks++){
#pragma unroll
            for (int mi = 0; mi < 4; mi++){
                const int r  = wm + mi * 16 + llo;
                const int pc = (ks * 4 + lhi) ^ (r & 7);
                af[ks][mi] = *(const short8*)(&As[cur][r * 64 + pc * 8]);
            }
#pragma unroll
            for (int ni = 0; ni < 2; ni++){
                const int r  = wn + ni * 16 + llo;
                const int pc = (ks * 4 + lhi) ^ (r & 7);
                bf0[ks][ni] = *(const short8*)(&Bs[cur][r * 64 + pc * 8]);
            }
        }
        __builtin_amdgcn_sched_barrier(0);
        if (more){ stageB(cur ^ 1, nk0, 0); stageB(cur ^ 1, nk0, 1); }
        __builtin_amdgcn_s_barrier();
        __builtin_amdgcn_sched_barrier(0);
        __builtin_amdgcn_s_setprio(1);
        MFMA_Q(acc0, af, bf0);
        __builtin_amdgcn_s_setprio(0);
        __builtin_amdgcn_s_barrier();
        __builtin_amdgcn_sched_barrier(0);

        // phase 1: bf1 ; MFMA q1
#pragma unroll
        for (int ks = 0; ks < 2; ks++)
#pragma unroll
            for (int ni = 0; ni < 2; ni++){
                const int r  = wn + 32 + ni * 16 + llo;
                const int pc = (ks * 4 + lhi) ^ (r & 7);
                bf1[ks][ni] = *(const short8*)(&Bs[cur][r * 64 + pc * 8]);
            }
        __builtin_amdgcn_sched_barrier(0);
        if (more){ stageB(cur ^ 1, nk0, 2); stageB(cur ^ 1, nk0, 3); WAITV(4); }
        else     { WAITV(0); }
        __builtin_amdgcn_s_barrier();
        __builtin_amdgcn_sched_barrier(0);
        __builtin_amdgcn_s_setprio(1);
        MFMA_Q(acc1, af, bf1);
        __builtin_amdgcn_s_setprio(0);
        __builtin_amdgcn_s_barrier();
        __builtin_amdgcn_sched_barrier(0);

        // phase 2: af(h1) ; MFMA q2
#pragma unroll
        for (int ks = 0; ks < 2; ks++)
#pragma unroll
            for (int mi = 0; mi < 4; mi++){
                const int r  = wm + 64 + mi * 16 + llo;
                const int pc = (ks * 4 + lhi) ^ (r & 7);
                af[ks][mi] = *(const short8*)(&As[cur][r * 64 + pc * 8]);
            }
        __builtin_amdgcn_sched_barrier(0);
        if (more){ stageA(cur ^ 1, nk0, 0); stageA(cur ^ 1, nk0, 2); }
        __builtin_amdgcn_s_barrier();
        __builtin_amdgcn_sched_barrier(0);
        __builtin_amdgcn_s_setprio(1);
        MFMA_Q(acc2, af, bf1);
        __builtin_amdgcn_s_setprio(0);
        __builtin_amdgcn_s_barrier();
        __builtin_amdgcn_sched_barrier(0);

        // phase 3: MFMA q3
        if (more){ stageA(cur ^ 1, nk0, 1); stageA(cur ^ 1, nk0, 3); WAITV(2); }
        __builtin_amdgcn_s_barrier();
        __builtin_amdgcn_sched_barrier(0);
        __builtin_amdgcn_s_setprio(1);
        MFMA_Q(acc3, af, bf0);
        __builtin_amdgcn_s_setprio(0);
        __builtin_amdgcn_s_barrier();
        __builtin_amdgcn_sched_barrier(0);

        cur ^= 1;
    }

    if constexpr (EPI == 4){
        // exp + store bf16 + per-row sums (denominator for fused softmax)
        float rp[2][4][4];
#pragma unroll
        for (int h = 0; h < 2; h++)
#pragma unroll
            for (int mi = 0; mi < 4; mi++)
#pragma unroll
                for (int j = 0; j < 4; j++) rp[h][mi][j] = 0.0f;

        auto epi4 = [&](f32x4 (&A)[8], int h, int cl){
#pragma unroll
            for (int mi = 0; mi < 4; mi++)
#pragma unroll
                for (int ni = 0; ni < 2; ni++){
                    const int n  = n0 + wn + cl * 32 + ni * 16 + llo;
                    const int mb = m0 + wm + h * 64 + mi * 16 + lhi * 4;
                    f32x4 v = A[mi * 2 + ni];
#pragma unroll
                    for (int j = 0; j < 4; j++){
                        float e = __expf(v[j] * scale);  // |s*scale| <~ 4, safe
                        unsigned short b = f2bf(e);
                        Cg[(long)(mb + j) * ldc + n] = b;
                        rp[h][mi][j] += bf2f(b);         // denom matches stored P
                    }
                }
        };
        epi4(acc0, 0, 0); epi4(acc1, 0, 1); epi4(acc2, 1, 1); epi4(acc3, 1, 0);

        // reduce across llo (16 lanes; masks 1,2,4,8 stay within lhi group)
#pragma unroll
        for (int h = 0; h < 2; h++)
#pragma unroll
            for (int mi = 0; mi < 4; mi++)
#pragma unroll
                for (int j = 0; j < 4; j++){
                    float v = rp[h][mi][j];
                    v += __shfl_xor(v, 1);
                    v += __shfl_xor(v, 2);
                    v += __shfl_xor(v, 4);
                    v += __shfl_xor(v, 8);
                    rp[h][mi][j] = v;
                }
        __syncthreads();               // all main-loop LDS traffic done
        float* LDSr = (float*)&As[0][0];  // 256 rows x 4 cg partials
        if (llo == 0){
#pragma unroll
            for (int h = 0; h < 2; h++)
#pragma unroll
                for (int mi = 0; mi < 4; mi++)
#pragma unroll
                    for (int j = 0; j < 4; j++)
                        LDSr[(rg * 128 + h * 64 + mi * 16 + lhi * 4 + j) * 4 + cg]
                            = rp[h][mi][j];
        }
        __syncthreads();
        if (t < 256){
            float s = (LDSr[t * 4 + 0] + LDSr[t * 4 + 1])
                    + (LDSr[t * 4 + 2] + LDSr[t * 4 + 3]);
            atomicAdd(&rs[(long)bz * sRS + m0 + t], s);
        }
    } else {
        auto epi = [&](f32x4 (&A)[8], int h, int cl){
#pragma unroll
            for (int mi = 0; mi < 4; mi++)
#pragma unroll
                for (int ni = 0; ni < 2; ni++){
                    const int n  = n0 + wn + cl * 32 + ni * 16 + llo;
                    const int mb = m0 + wm + h * 64 + mi * 16 + lhi * 4;
                    f32x4 v = A[mi * 2 + ni];
#pragma unroll
                    for (int j = 0; j < 4; j++){
                        float val = v[j] * scale;
                        if (EPI == 1) val += bias[n];
                        store1(&Cg[(long)(mb + j) * ldc + n], val);
                    }
                }
        };
        epi(acc0, 0, 0); epi(acc1, 0, 1); epi(acc2, 1, 1); epi(acc3, 1, 0);
    }
}

// ============================================================================
// 128x128 2-phase GEMM. EPI: 0 none, 1 +bias[n], 2 +bias[m],
// 3 +bias[m]+resid[m*ldc+n], 5 *1/rs[m] (softmax denominator)
// ============================================================================
template<typename OutT, int EPI>
__global__ __launch_bounds__(256)
void gemm_nt(const unsigned short* __restrict__ Ag,
             const unsigned short* __restrict__ Bg,
             OutT* __restrict__ Cg,
             int K, int lda, int ldb, int ldc,
             long sA, long sB, long sC,
             const float* __restrict__ bias,
             const float* __restrict__ resid, long sR,
             const float* __restrict__ rs, long sRS,
             float scale)
{
    const int gx = gridDim.x, gy = gridDim.y;
    const int nwg  = gx * gy * (int)gridDim.z;
    const int orig = blockIdx.x + gx * (blockIdx.y + gy * blockIdx.z);
    const int cpx  = nwg >> 3;
    const int nid  = (orig & 7) * cpx + (orig >> 3);
    const int bx   = nid % gx;
    const int tmp  = nid / gx;
    const int by   = tmp % gy;
    const int bz   = tmp / gy;

    Ag += (long)bz * sA;
    Bg += (long)bz * sB;
    Cg += (long)bz * sC;
    const int m0 = by * 128;
    const int n0 = bx * 128;

    __shared__ unsigned short As[2][128 * 64];
    __shared__ unsigned short Bs[2][128 * 64];

    const int t    = threadIdx.x;
    const int wave = t >> 6;
    const int lane = t & 63;
    const int wm   = (wave >> 1) << 6;
    const int wn   = (wave & 1) << 6;
    const int lhi  = lane >> 4;
    const int llo  = lane & 15;

    f32x4 acc[4][4];
#pragma unroll
    for (int i = 0; i < 4; i++)
#pragma unroll
        for (int j = 0; j < 4; j++) acc[i][j] = (f32x4)(0.0f);

    auto stage = [&](int bi, int k0){
#pragma unroll
        for (int i = 0; i < 4; i++){
            const int tt = i * 256 + t;
            const int r  = tt >> 3;
            const int cb = tt & 7;
            const int cs = cb ^ (r & 7);
            GLDS(Ag + (long)(m0 + r) * lda + k0 + cs * 8, &As[bi][i * 2048 + wave * 512]);
            GLDS(Bg + (long)(n0 + r) * ldb + k0 + cs * 8, &Bs[bi][i * 2048 + wave * 512]);
        }
    };

    const int nt = K >> 6;
    stage(0, 0);
    __syncthreads();

    int cur = 0;
    for (int kt = 0; kt < nt; kt++){
        if (kt + 1 < nt) stage(cur ^ 1, (kt + 1) << 6);
#pragma unroll
        for (int ksub = 0; ksub < 2; ksub++){
            short8 af[4], bf[4];
#pragma unroll
            for (int mi = 0; mi < 4; mi++){
                const int r  = wm + mi * 16 + llo;
                const int cs = (ksub * 4 + lhi) ^ (r & 7);
                af[mi] = *(const short8*)(&As[cur][r * 64 + cs * 8]);
            }
#pragma unroll
            for (int ni = 0; ni < 4; ni++){
                const int r  = wn + ni * 16 + llo;
                const int cs = (ksub * 4 + lhi) ^ (r & 7);
                bf[ni] = *(const short8*)(&Bs[cur][r * 64 + cs * 8]);
            }
#pragma unroll
            for (int mi = 0; mi < 4; mi++)
#pragma unroll
                for (int ni = 0; ni < 4; ni++)
                    acc[mi][ni] = __builtin_amdgcn_mfma_f32_16x16x32_bf16(
                        af[mi], bf[ni], acc[mi][ni], 0, 0, 0);
        }
        __syncthreads();
        cur ^= 1;
    }

#pragma unroll
    for (int mi = 0; mi < 4; mi++){
#pragma unroll
        for (int ni = 0; ni < 4; ni++){
            const int n  = n0 + wn + ni * 16 + llo;
            const int mb = m0 + wm + mi * 16 + lhi * 4;
            f32x4 v = acc[mi][ni];
#pragma unroll
            for (int j = 0; j < 4; j++){
                const int m = mb + j;
                float val = v[j] * scale;
                if (EPI == 1) val += bias[n];
                if (EPI == 2) val += bias[m];
                if (EPI == 3) val += bias[m] + resid[(long)bz * sR + (long)m * ldc + n];
                if (EPI == 5) val /= rs[(long)bz * sRS + m];
                store1(&Cg[(long)m * ldc + n], val);
            }
        }
    }
}

// ---- GroupNorm: B=8, C=512, L=2048, G=8 -> 64 (b,g) groups ----

__global__ void gn_partial(const float* __restrict__ x, float* __restrict__ part){
    const long base = (long)blockIdx.x * 8192;
    const float4* xp = (const float4*)(x + base);
    float s = 0.f, ss = 0.f;
    for (int i = threadIdx.x; i < 2048; i += 256){
        float4 v = xp[i];
        s  += (v.x + v.y) + (v.z + v.w);
        ss += (v.x * v.x + v.y * v.y) + (v.z * v.z + v.w * v.w);
    }
    for (int o = 32; o; o >>= 1){ s += __shfl_down(s, o); ss += __shfl_down(ss, o); }
    __shared__ float rsd[4], rss[4];
    const int wave = threadIdx.x >> 6, lane = threadIdx.x & 63;
    if (lane == 0){ rsd[wave] = s; rss[wave] = ss; }
    __syncthreads();
    if (threadIdx.x == 0){
        part[blockIdx.x * 2]     = (rsd[0] + rsd[1]) + (rsd[2] + rsd[3]);
        part[blockIdx.x * 2 + 1] = (rss[0] + rss[1]) + (rss[2] + rss[3]);
    }
}

__global__ void gn_final(const float* __restrict__ part, float* __restrict__ stats){
    const int bg = threadIdx.x;
    if (bg >= 64) return;
    float s = 0.f, ss = 0.f;
    for (int c = 0; c < 16; c++){
        s  += part[(bg * 16 + c) * 2];
        ss += part[(bg * 16 + c) * 2 + 1];
    }
    const float inv_n = 1.0f / 131072.0f;
    const float mean = s * inv_n;
    const float var  = ss * inv_n - mean * mean;
    stats[bg * 2]     = mean;
    stats[bg * 2 + 1] = rsqrtf(var + 1e-6f);
}

__global__ void norm_transpose(const float* __restrict__ x, const float* __restrict__ stats,
                               const float* __restrict__ gamma, const float* __restrict__ beta,
                               unsigned short* __restrict__ ht){
    const int b = blockIdx.z, c0 = blockIdx.y * 64, l0 = blockIdx.x * 64;
    const int bg = b * 8 + (c0 >> 6);
    const float mean = stats[bg * 2], rstd = stats[bg * 2 + 1];
    __shared__ unsigned short tile[64][66];
    const float* xb = x + (long)b * 1048576;
    const int t = threadIdx.x;
#pragma unroll
    for (int i = 0; i < 16; i++){
        const int idx = i * 256 + t;
        const int c = idx >> 6, l = idx & 63;
        float v = xb[(long)(c0 + c) * 2048 + l0 + l];
        v = (v - mean) * rstd * gamma[c0 + c] + beta[c0 + c];
        tile[l][c] = f2bf(v);
    }
    __syncthreads();
    unsigned short* htb = ht + (long)b * 1048576;
#pragma unroll
    for (int i = 0; i < 16; i++){
        const int idx = i * 256 + t;
        const int l = idx >> 6, c = idx & 63;
        htb[(long)(l0 + l) * 512 + c0 + c] = tile[l][c];
    }
}

// weights -> bf16 (wq,wk,wv,wo contiguous) + concat bq|bk fp32 into bqk
__global__ void weights_to_bf16(const float4* __restrict__ wq, const float4* __restrict__ wk,
                                const float4* __restrict__ wv, const float4* __restrict__ wo,
                                const float* __restrict__ bq, const float* __restrict__ bk,
                                ushort4v* __restrict__ out, float* __restrict__ bqk){
    const int i = blockIdx.x * 256 + threadIdx.x;
    if (i < 262144){
        const int w = i >> 16, off = i & 65535;
        const float4* src = (w == 0) ? wq : (w == 1) ? wk : (w == 2) ? wv : wo;
        float4 v = src[off];
        ushort4v o;
        o.x = f2bf(v.x); o.y = f2bf(v.y); o.z = f2bf(v.z); o.w = f2bf(v.w);
        out[i] = o;
    } else {
        const int j = i - 262144;
        if (j < 1024) bqk[j] = (j < 512) ? bq[j] : bk[j - 512];
    }
}

// ---- workspace layout (bytes) ----
enum : long {
    OFF_WQ  = 0,                    // 4 weights bf16, contiguous (wq|wk|wv|wo)
    OFF_BQK = 2097152,              // 1024 fp32 (bq|bk)
    OFF_RS  = OFF_BQK + 4096,       // rowsum [B][L] fp32 (64 KB, memset 0)
    OFF_HT  = OFF_RS  + 65536,      // [B][L][C] bf16
    OFF_QK  = OFF_HT  + 16777216,   // [B][L][1024] bf16 (q cols 0-511, k 512-1023)
    OFF_V   = OFF_QK  + 33554432,   // [B][C][L] bf16
    OFF_H2  = OFF_V   + 16777216,   // [B][L][C] bf16
    OFF_P   = OFF_H2  + 16777216,   // [B][L][L] bf16 = exp(scores)
    OFF_GNP = OFF_P   + 67108864,
    OFF_GNS = OFF_GNP + 8192,
    OFF_END = OFF_GNS + 512
};

extern "C" void kernel_launch(void* const* d_in, const int* in_sizes, int n_in,
                              void* d_out, int out_size, void* d_ws, size_t ws_size,
                              hipStream_t stream)
{
    const float* x     = (const float*)d_in[0];
    const float* gamma = (const float*)d_in[1];
    const float* beta  = (const float*)d_in[2];
    const float* wq    = (const float*)d_in[3];
    const float* bq    = (const float*)d_in[4];
    const float* wk    = (const float*)d_in[5];
    const float* bk    = (const float*)d_in[6];
    const float* wv    = (const float*)d_in[7];
    const float* bv    = (const float*)d_in[8];
    const float* wo    = (const float*)d_in[9];
    const float* bo    = (const float*)d_in[10];
    float* out = (float*)d_out;
    char* ws = (char*)d_ws;

    if (ws_size < (size_t)OFF_END){
        fprintf(stderr, "kernel_launch: ws too small (%zu < %ld)\n", ws_size, (long)OFF_END);
        return;
    }

    unsigned short* WQb = (unsigned short*)(ws + OFF_WQ);
    unsigned short* WVb = WQb + 2 * 262144;          // wv at slot 2
    unsigned short* WOb = WQb + 3 * 262144;          // wo at slot 3
    float*          BQK = (float*)(ws + OFF_BQK);
    float*          RS  = (float*)(ws + OFF_RS);
    unsigned short* HT  = (unsigned short*)(ws + OFF_HT);
    unsigned short* QK  = (unsigned short*)(ws + OFF_QK);
    unsigned short* V   = (unsigned short*)(ws + OFF_V);
    unsigned short* H2  = (unsigned short*)(ws + OFF_H2);
    unsigned short* P   = (unsigned short*)(ws + OFF_P);
    float*          GNP = (float*)(ws + OFF_GNP);
    float*          GNS = (float*)(ws + OFF_GNS);

    const long LC  = 1048576;   // 2048*512
    const long LQK = 2097152;   // 2048*1024
    const long LL  = 4194304;   // 2048*2048

    hipMemsetAsync(RS, 0, 65536, stream);   // rowsum accumulators

    weights_to_bf16<<<1028, 256, 0, stream>>>(
        (const float4*)wq, (const float4*)wk, (const float4*)wv, (const float4*)wo,
        bq, bk, (ushort4v*)WQb, BQK);

    gn_partial<<<1024, 256, 0, stream>>>(x, GNP);
    gn_final<<<1, 64, 0, stream>>>(GNP, GNS);
    norm_transpose<<<dim3(32, 8, 8), 256, 0, stream>>>(x, GNS, gamma, beta, HT);

    // fused q|k projection: qk[l, 0:512]=q, [512:1024]=k  (M=2048,N=1024,K=512)
    gemm_nt<unsigned short, 1><<<dim3(8, 16, 8), 256, 0, stream>>>(
        HT, WQb, QK, 512, 512, 512, 1024, LC, 0, LQK, BQK, nullptr, 0, nullptr, 0, 1.0f);
    // v[o,l]  (M=512,N=2048,K=512)
    gemm_nt<unsigned short, 2><<<dim3(16, 4, 8), 256, 0, stream>>>(
        WVb, HT, V, 512, 512, 512, 2048, 0, LC, LC, bv, nullptr, 0, nullptr, 0, 1.0f);

    // P = exp(q.k/sqrt(C)) + row-sum atomics  (M=N=2048,K=512, 8-phase 256^2)
    gemm256<unsigned short, 4><<<dim3(8, 8, 8), 512, 0, stream>>>(
        QK, QK + 512, P, 512, 1024, 1024, 2048, LQK, LQK, LL,
        nullptr, RS, 2048, 0.04419417382f);

    // h2_t[i,c] = (sum_j P[i,j] v[c,j]) / rowsum[i]  (M=2048,N=512,K=2048)
    gemm_nt<unsigned short, 5><<<dim3(4, 16, 8), 256, 0, stream>>>(
        P, V, H2, 2048, 2048, 2048, 512, LL, LC, LC, nullptr, nullptr, 0, RS, 2048, 1.0f);

    // out[o,l] = sum_c wo[o,c] h2_t[l,c] + bo[o] + x[o,l]  (M=512,N=2048,K=512)
    gemm_nt<float, 3><<<dim3(16, 4, 8), 256, 0, stream>>>(
        WOb, H2, out, 512, 512, 512, 2048, 0, LC, LC, bo, x, LC, nullptr, 0, 1.0f);
}

// Round 8
// 254.594 us; speedup vs baseline: 1.2139x; 1.0606x over previous
//
#include <hip/hip_runtime.h>
#include <hip/hip_bf16.h>
#include <cstdio>

typedef __attribute__((ext_vector_type(8))) short short8;
typedef __attribute__((ext_vector_type(8))) unsigned short ushort8;
typedef __attribute__((ext_vector_type(4))) float f32x4;
typedef __attribute__((ext_vector_type(4))) unsigned short ushort4v;

__device__ inline unsigned short f2bf(float f){
    unsigned int u = __float_as_uint(f);
    unsigned int r = (u + 0x7fffu + ((u >> 16) & 1u)) >> 16;
    return (unsigned short)r;
}
__device__ inline float bf2f(unsigned short b){
    return __uint_as_float((unsigned int)b << 16);
}

__device__ inline void store1(float* p, float v){ *p = v; }
__device__ inline void store1(unsigned short* p, float v){ *p = f2bf(v); }

#define GLDS(gp, lp) __builtin_amdgcn_global_load_lds( \
    (const __attribute__((address_space(1))) void*)(gp), \
    (__attribute__((address_space(3))) void*)(lp), 16, 0, 0)

#define WAITV(N) asm volatile("s_waitcnt vmcnt(" #N ")" ::: "memory")

#define MFMA_Q(ACC, AF, BF) \
    _Pragma("unroll") \
    for (int ks = 0; ks < 2; ks++) \
        _Pragma("unroll") \
        for (int mi = 0; mi < 4; mi++) \
            _Pragma("unroll") \
            for (int ni = 0; ni < 2; ni++) \
                ACC[mi * 2 + ni] = __builtin_amdgcn_mfma_f32_16x16x32_bf16( \
                    AF[ks][mi], BF[ks][ni], ACC[mi * 2 + ni], 0, 0, 0);

// ============================================================================
// 256x256 8-phase GEMM, fragment-reuse schedule (24 ds_read_b128/wave/K-tile).
// EPI: 1 +bias[n]; 4 = P-with-exp: store bf16 exp(scale*s), write per-block
// row-sum PARTIALS (fp32, non-atomic) to rs[bz*sRS + bx*2048 + m] — every
// slot is written, so no pre-zeroing needed.
// Ledger: p1 vmcnt(4), p3 vmcnt(2) (see round-4 derivation).
// ============================================================================
template<typename OutT, int EPI>
__global__ __launch_bounds__(512, 2)
void gemm256(const unsigned short* __restrict__ Ag,
             const unsigned short* __restrict__ Bg,
             OutT* __restrict__ Cg,
             int K, int lda, int ldb, int ldc,
             long sA, long sB, long sC,
             const float* __restrict__ bias,
             float* __restrict__ rs, long sRS,
             float scale)
{
    const int gx = gridDim.x, gy = gridDim.y;
    const int nwg  = gx * gy * (int)gridDim.z;
    const int orig = blockIdx.x + gx * (blockIdx.y + gy * blockIdx.z);
    const int cpx  = nwg >> 3;
    const int nid  = (orig & 7) * cpx + (orig >> 3);
    const int bx   = nid % gx;
    const int tmp  = nid / gx;
    const int by   = tmp % gy;
    const int bz   = tmp / gy;

    Ag += (long)bz * sA;
    Bg += (long)bz * sB;
    Cg += (long)bz * sC;
    const int m0 = by * 256;
    const int n0 = bx * 256;

    __shared__ unsigned short As[2][16384];  // 2 x 32 KB
    __shared__ unsigned short Bs[2][16384];  // 2 x 32 KB (128 KB total)

    const int t    = threadIdx.x;
    const int wave = t >> 6;
    const int lane = t & 63;
    const int rg   = wave >> 2;
    const int cg   = wave & 3;
    const int wm   = rg * 128;
    const int wn   = cg * 64;
    const int lhi  = lane >> 4;
    const int llo  = lane & 15;

    f32x4 acc0[8], acc1[8], acc2[8], acc3[8];
#pragma unroll
    for (int f = 0; f < 8; f++){
        acc0[f] = (f32x4)(0.0f); acc1[f] = (f32x4)(0.0f);
        acc2[f] = (f32x4)(0.0f); acc3[f] = (f32x4)(0.0f);
    }

    const int s_rr = t >> 3, s_cb = t & 7;
    const int s_cs = s_cb ^ (s_rr & 7);
    auto stageA = [&](int bi, int k0, int j){
        GLDS(Ag + (long)(m0 + j * 64 + s_rr) * lda + k0 + s_cs * 8,
             &As[bi][j * 4096 + wave * 512]);
    };
    auto stageB = [&](int bi, int k0, int j){
        GLDS(Bg + (long)(n0 + j * 64 + s_rr) * ldb + k0 + s_cs * 8,
             &Bs[bi][j * 4096 + wave * 512]);
    };

    const int nt = K >> 6;
    stageB(0, 0, 0); stageB(0, 0, 1); stageB(0, 0, 2); stageB(0, 0, 3);
    stageA(0, 0, 0); stageA(0, 0, 2); stageA(0, 0, 1); stageA(0, 0, 3);
    WAITV(2);
    __builtin_amdgcn_s_barrier();
    __builtin_amdgcn_sched_barrier(0);

    int cur = 0;
    for (int kt = 0; kt < nt; kt++){
        const bool more = (kt + 1 < nt);
        const int nk0 = (kt + 1) << 6;
        short8 af[2][4], bf0[2][2], bf1[2][2];

        // phase 0: af(h0)+bf0 ; MFMA q0
#pragma unroll
        for (int ks = 0; ks < 2; ks++){
#pragma unroll
            for (int mi = 0; mi < 4; mi++){
                const int r  = wm + mi * 16 + llo;
                const int pc = (ks * 4 + lhi) ^ (r & 7);
                af[ks][mi] = *(const short8*)(&As[cur][r * 64 + pc * 8]);
            }
#pragma unroll
            for (int ni = 0; ni < 2; ni++){
                const int r  = wn + ni * 16 + llo;
                const int pc = (ks * 4 + lhi) ^ (r & 7);
                bf0[ks][ni] = *(const short8*)(&Bs[cur][r * 64 + pc * 8]);
            }
        }
        __builtin_amdgcn_sched_barrier(0);
        if (more){ stageB(cur ^ 1, nk0, 0); stageB(cur ^ 1, nk0, 1); }
        __builtin_amdgcn_s_barrier();
        __builtin_amdgcn_sched_barrier(0);
        __builtin_amdgcn_s_setprio(1);
        MFMA_Q(acc0, af, bf0);
        __builtin_amdgcn_s_setprio(0);
        __builtin_amdgcn_s_barrier();
        __builtin_amdgcn_sched_barrier(0);

        // phase 1: bf1 ; MFMA q1
#pragma unroll
        for (int ks = 0; ks < 2; ks++)
#pragma unroll
            for (int ni = 0; ni < 2; ni++){
                const int r  = wn + 32 + ni * 16 + llo;
                const int pc = (ks * 4 + lhi) ^ (r & 7);
                bf1[ks][ni] = *(const short8*)(&Bs[cur][r * 64 + pc * 8]);
            }
        __builtin_amdgcn_sched_barrier(0);
        if (more){ stageB(cur ^ 1, nk0, 2); stageB(cur ^ 1, nk0, 3); WAITV(4); }
        else     { WAITV(0); }
        __builtin_amdgcn_s_barrier();
        __builtin_amdgcn_sched_barrier(0);
        __builtin_amdgcn_s_setprio(1);
        MFMA_Q(acc1, af, bf1);
        __builtin_amdgcn_s_setprio(0);
        __builtin_amdgcn_s_barrier();
        __builtin_amdgcn_sched_barrier(0);

        // phase 2: af(h1) ; MFMA q2
#pragma unroll
        for (int ks = 0; ks < 2; ks++)
#pragma unroll
            for (int mi = 0; mi < 4; mi++){
                const int r  = wm + 64 + mi * 16 + llo;
                const int pc = (ks * 4 + lhi) ^ (r & 7);
                af[ks][mi] = *(const short8*)(&As[cur][r * 64 + pc * 8]);
            }
        __builtin_amdgcn_sched_barrier(0);
        if (more){ stageA(cur ^ 1, nk0, 0); stageA(cur ^ 1, nk0, 2); }
        __builtin_amdgcn_s_barrier();
        __builtin_amdgcn_sched_barrier(0);
        __builtin_amdgcn_s_setprio(1);
        MFMA_Q(acc2, af, bf1);
        __builtin_amdgcn_s_setprio(0);
        __builtin_amdgcn_s_barrier();
        __builtin_amdgcn_sched_barrier(0);

        // phase 3: MFMA q3
        if (more){ stageA(cur ^ 1, nk0, 1); stageA(cur ^ 1, nk0, 3); WAITV(2); }
        __builtin_amdgcn_s_barrier();
        __builtin_amdgcn_sched_barrier(0);
        __builtin_amdgcn_s_setprio(1);
        MFMA_Q(acc3, af, bf0);
        __builtin_amdgcn_s_setprio(0);
        __builtin_amdgcn_s_barrier();
        __builtin_amdgcn_sched_barrier(0);

        cur ^= 1;
    }

    if constexpr (EPI == 4){
        // exp + store bf16 + per-row sum partials (softmax denominator)
        float rp[2][4][4];
#pragma unroll
        for (int h = 0; h < 2; h++)
#pragma unroll
            for (int mi = 0; mi < 4; mi++)
#pragma unroll
                for (int j = 0; j < 4; j++) rp[h][mi][j] = 0.0f;

        auto epi4 = [&](f32x4 (&A)[8], int h, int cl){
#pragma unroll
            for (int mi = 0; mi < 4; mi++)
#pragma unroll
                for (int ni = 0; ni < 2; ni++){
                    const int n  = n0 + wn + cl * 32 + ni * 16 + llo;
                    const int mb = m0 + wm + h * 64 + mi * 16 + lhi * 4;
                    f32x4 v = A[mi * 2 + ni];
#pragma unroll
                    for (int j = 0; j < 4; j++){
                        float e = __expf(v[j] * scale);  // |s*scale| <~ 4, safe
                        Cg[(long)(mb + j) * ldc + n] = f2bf(e);
                        rp[h][mi][j] += e;
                    }
                }
        };
        epi4(acc0, 0, 0); epi4(acc1, 0, 1); epi4(acc2, 1, 1); epi4(acc3, 1, 0);

        // reduce across llo (masks 1,2,4,8 stay within the lhi group)
#pragma unroll
        for (int h = 0; h < 2; h++)
#pragma unroll
            for (int mi = 0; mi < 4; mi++)
#pragma unroll
                for (int j = 0; j < 4; j++){
                    float v = rp[h][mi][j];
                    v += __shfl_xor(v, 1);
                    v += __shfl_xor(v, 2);
                    v += __shfl_xor(v, 4);
                    v += __shfl_xor(v, 8);
                    rp[h][mi][j] = v;
                }
        __syncthreads();
        float* LDSr = (float*)&As[0][0];  // 256 rows x 4 cg partials
        if (llo == 0){
#pragma unroll
            for (int h = 0; h < 2; h++)
#pragma unroll
                for (int mi = 0; mi < 4; mi++)
#pragma unroll
                    for (int j = 0; j < 4; j++)
                        LDSr[(rg * 128 + h * 64 + mi * 16 + lhi * 4 + j) * 4 + cg]
                            = rp[h][mi][j];
        }
        __syncthreads();
        if (t < 256){
            float s = (LDSr[t * 4 + 0] + LDSr[t * 4 + 1])
                    + (LDSr[t * 4 + 2] + LDSr[t * 4 + 3]);
            rs[(long)bz * sRS + (long)bx * 2048 + m0 + t] = s;  // plain store
        }
    } else {
        auto epi = [&](f32x4 (&A)[8], int h, int cl){
#pragma unroll
            for (int mi = 0; mi < 4; mi++)
#pragma unroll
                for (int ni = 0; ni < 2; ni++){
                    const int n  = n0 + wn + cl * 32 + ni * 16 + llo;
                    const int mb = m0 + wm + h * 64 + mi * 16 + lhi * 4;
                    f32x4 v = A[mi * 2 + ni];
#pragma unroll
                    for (int j = 0; j < 4; j++){
                        float val = v[j] * scale;
                        if (EPI == 1) val += bias[n];
                        store1(&Cg[(long)(mb + j) * ldc + n], val);
                    }
                }
        };
        epi(acc0, 0, 0); epi(acc1, 0, 1); epi(acc2, 1, 1); epi(acc3, 1, 0);
    }
}

// ============================================================================
// 128x128 2-phase GEMM. EPI: 0 none, 1 +bias[n], 2 +bias[m],
// 3 +bias[m]+resid[m*ldc+n], 5 *1/sum8(rs partials) (softmax denominator)
// ============================================================================
template<typename OutT, int EPI>
__global__ __launch_bounds__(256)
void gemm_nt(const unsigned short* __restrict__ Ag,
             const unsigned short* __restrict__ Bg,
             OutT* __restrict__ Cg,
             int K, int lda, int ldb, int ldc,
             long sA, long sB, long sC,
             const float* __restrict__ bias,
             const float* __restrict__ resid, long sR,
             const float* __restrict__ rs, long sRS,
             float scale)
{
    const int gx = gridDim.x, gy = gridDim.y;
    const int nwg  = gx * gy * (int)gridDim.z;
    const int orig = blockIdx.x + gx * (blockIdx.y + gy * blockIdx.z);
    const int cpx  = nwg >> 3;
    const int nid  = (orig & 7) * cpx + (orig >> 3);
    const int bx   = nid % gx;
    const int tmp  = nid / gx;
    const int by   = tmp % gy;
    const int bz   = tmp / gy;

    Ag += (long)bz * sA;
    Bg += (long)bz * sB;
    Cg += (long)bz * sC;
    const int m0 = by * 128;
    const int n0 = bx * 128;

    __shared__ unsigned short As[2][128 * 64];
    __shared__ unsigned short Bs[2][128 * 64];

    const int t    = threadIdx.x;
    const int wave = t >> 6;
    const int lane = t & 63;
    const int wm   = (wave >> 1) << 6;
    const int wn   = (wave & 1) << 6;
    const int lhi  = lane >> 4;
    const int llo  = lane & 15;

    f32x4 acc[4][4];
#pragma unroll
    for (int i = 0; i < 4; i++)
#pragma unroll
        for (int j = 0; j < 4; j++) acc[i][j] = (f32x4)(0.0f);

    auto stage = [&](int bi, int k0){
#pragma unroll
        for (int i = 0; i < 4; i++){
            const int tt = i * 256 + t;
            const int r  = tt >> 3;
            const int cb = tt & 7;
            const int cs = cb ^ (r & 7);
            GLDS(Ag + (long)(m0 + r) * lda + k0 + cs * 8, &As[bi][i * 2048 + wave * 512]);
            GLDS(Bg + (long)(n0 + r) * ldb + k0 + cs * 8, &Bs[bi][i * 2048 + wave * 512]);
        }
    };

    const int nt = K >> 6;
    stage(0, 0);
    __syncthreads();

    int cur = 0;
    for (int kt = 0; kt < nt; kt++){
        if (kt + 1 < nt) stage(cur ^ 1, (kt + 1) << 6);
#pragma unroll
        for (int ksub = 0; ksub < 2; ksub++){
            short8 af[4], bf[4];
#pragma unroll
            for (int mi = 0; mi < 4; mi++){
                const int r  = wm + mi * 16 + llo;
                const int cs = (ksub * 4 + lhi) ^ (r & 7);
                af[mi] = *(const short8*)(&As[cur][r * 64 + cs * 8]);
            }
#pragma unroll
            for (int ni = 0; ni < 4; ni++){
                const int r  = wn + ni * 16 + llo;
                const int cs = (ksub * 4 + lhi) ^ (r & 7);
                bf[ni] = *(const short8*)(&Bs[cur][r * 64 + cs * 8]);
            }
#pragma unroll
            for (int mi = 0; mi < 4; mi++)
#pragma unroll
                for (int ni = 0; ni < 4; ni++)
                    acc[mi][ni] = __builtin_amdgcn_mfma_f32_16x16x32_bf16(
                        af[mi], bf[ni], acc[mi][ni], 0, 0, 0);
        }
        __syncthreads();
        cur ^= 1;
    }

    float inv_d[4][4];
    if constexpr (EPI == 5){
#pragma unroll
        for (int mi = 0; mi < 4; mi++)
#pragma unroll
            for (int j = 0; j < 4; j++){
                const int m = m0 + wm + mi * 16 + lhi * 4 + j;
                float s = 0.f;
#pragma unroll
                for (int p = 0; p < 8; p++)
                    s += rs[(long)bz * sRS + p * 2048 + m];
                inv_d[mi][j] = 1.0f / s;
            }
    }

#pragma unroll
    for (int mi = 0; mi < 4; mi++){
#pragma unroll
        for (int ni = 0; ni < 4; ni++){
            const int n  = n0 + wn + ni * 16 + llo;
            const int mb = m0 + wm + mi * 16 + lhi * 4;
            f32x4 v = acc[mi][ni];
#pragma unroll
            for (int j = 0; j < 4; j++){
                const int m = mb + j;
                float val = v[j] * scale;
                if (EPI == 1) val += bias[n];
                if (EPI == 2) val += bias[m];
                if (EPI == 3) val += bias[m] + resid[(long)bz * sR + (long)m * ldc + n];
                if (EPI == 5) val *= inv_d[mi][j];
                store1(&Cg[(long)m * ldc + n], val);
            }
        }
    }
}

// ---- GroupNorm: B=8, C=512, L=2048, G=8 -> 64 (b,g) groups ----

__global__ void gn_partial(const float* __restrict__ x, float* __restrict__ part){
    const long base = (long)blockIdx.x * 8192;
    const float4* xp = (const float4*)(x + base);
    float s = 0.f, ss = 0.f;
    for (int i = threadIdx.x; i < 2048; i += 256){
        float4 v = xp[i];
        s  += (v.x + v.y) + (v.z + v.w);
        ss += (v.x * v.x + v.y * v.y) + (v.z * v.z + v.w * v.w);
    }
    for (int o = 32; o; o >>= 1){ s += __shfl_down(s, o); ss += __shfl_down(ss, o); }
    __shared__ float rsd[4], rss[4];
    const int wave = threadIdx.x >> 6, lane = threadIdx.x & 63;
    if (lane == 0){ rsd[wave] = s; rss[wave] = ss; }
    __syncthreads();
    if (threadIdx.x == 0){
        part[blockIdx.x * 2]     = (rsd[0] + rsd[1]) + (rsd[2] + rsd[3]);
        part[blockIdx.x * 2 + 1] = (rss[0] + rss[1]) + (rss[2] + rss[3]);
    }
}

// normalize + affine + transpose; computes group stats from gn_partial output
__global__ void norm_transpose(const float* __restrict__ x, const float* __restrict__ part,
                               const float* __restrict__ gamma, const float* __restrict__ beta,
                               unsigned short* __restrict__ ht){
    const int b = blockIdx.z, c0 = blockIdx.y * 64, l0 = blockIdx.x * 64;
    const int bg = b * 8 + (c0 >> 6);
    __shared__ float sm[2];
    const int t = threadIdx.x;
    if (t < 16){
        float s  = part[(bg * 16 + t) * 2];
        float ss = part[(bg * 16 + t) * 2 + 1];
        s  += __shfl_xor(s, 1);  ss += __shfl_xor(ss, 1);
        s  += __shfl_xor(s, 2);  ss += __shfl_xor(ss, 2);
        s  += __shfl_xor(s, 4);  ss += __shfl_xor(ss, 4);
        s  += __shfl_xor(s, 8);  ss += __shfl_xor(ss, 8);
        if (t == 0){
            const float inv_n = 1.0f / 131072.0f;
            const float mean = s * inv_n;
            const float var  = ss * inv_n - mean * mean;
            sm[0] = mean; sm[1] = rsqrtf(var + 1e-6f);
        }
    }
    __syncthreads();
    const float mean = sm[0], rstd = sm[1];
    __shared__ unsigned short tile[64][66];
    const float* xb = x + (long)b * 1048576;
#pragma unroll
    for (int i = 0; i < 16; i++){
        const int idx = i * 256 + t;
        const int c = idx >> 6, l = idx & 63;
        float v = xb[(long)(c0 + c) * 2048 + l0 + l];
        v = (v - mean) * rstd * gamma[c0 + c] + beta[c0 + c];
        tile[l][c] = f2bf(v);
    }
    __syncthreads();
    unsigned short* htb = ht + (long)b * 1048576;
#pragma unroll
    for (int i = 0; i < 16; i++){
        const int idx = i * 256 + t;
        const int l = idx >> 6, c = idx & 63;
        htb[(long)(l0 + l) * 512 + c0 + c] = tile[l][c];
    }
}

// weights -> bf16 (wq,wk,wv,wo contiguous) + concat bq|bk fp32 into bqk
__global__ void weights_to_bf16(const float4* __restrict__ wq, const float4* __restrict__ wk,
                                const float4* __restrict__ wv, const float4* __restrict__ wo,
                                const float* __restrict__ bq, const float* __restrict__ bk,
                                ushort4v* __restrict__ out, float* __restrict__ bqk){
    const int i = blockIdx.x * 256 + threadIdx.x;
    if (i < 262144){
        const int w = i >> 16, off = i & 65535;
        const float4* src = (w == 0) ? wq : (w == 1) ? wk : (w == 2) ? wv : wo;
        float4 v = src[off];
        ushort4v o;
        o.x = f2bf(v.x); o.y = f2bf(v.y); o.z = f2bf(v.z); o.w = f2bf(v.w);
        out[i] = o;
    } else {
        const int j = i - 262144;
        if (j < 1024) bqk[j] = (j < 512) ? bq[j] : bk[j - 512];
    }
}

// ---- workspace layout (bytes) ----
enum : long {
    OFF_WQ  = 0,                    // 4 weights bf16, contiguous (wq|wk|wv|wo)
    OFF_BQK = 2097152,              // 1024 fp32 (bq|bk)
    OFF_RS  = OFF_BQK + 4096,       // rowsum partials [B][8][L] fp32 (512 KB)
    OFF_HT  = OFF_RS  + 524288,     // [B][L][C] bf16
    OFF_QK  = OFF_HT  + 16777216,   // [B][L][1024] bf16 (q cols 0-511, k 512-1023)
    OFF_V   = OFF_QK  + 33554432,   // [B][C][L] bf16
    OFF_H2  = OFF_V   + 16777216,   // [B][L][C] bf16
    OFF_P   = OFF_H2  + 16777216,   // [B][L][L] bf16 = exp(scores)
    OFF_GNP = OFF_P   + 67108864,
    OFF_END = OFF_GNP + 8192
};

extern "C" void kernel_launch(void* const* d_in, const int* in_sizes, int n_in,
                              void* d_out, int out_size, void* d_ws, size_t ws_size,
                              hipStream_t stream)
{
    const float* x     = (const float*)d_in[0];
    const float* gamma = (const float*)d_in[1];
    const float* beta  = (const float*)d_in[2];
    const float* wq    = (const float*)d_in[3];
    const float* bq    = (const float*)d_in[4];
    const float* wk    = (const float*)d_in[5];
    const float* bk    = (const float*)d_in[6];
    const float* wv    = (const float*)d_in[7];
    const float* bv    = (const float*)d_in[8];
    const float* wo    = (const float*)d_in[9];
    const float* bo    = (const float*)d_in[10];
    float* out = (float*)d_out;
    char* ws = (char*)d_ws;

    if (ws_size < (size_t)OFF_END){
        fprintf(stderr, "kernel_launch: ws too small (%zu < %ld)\n", ws_size, (long)OFF_END);
        return;
    }

    unsigned short* WQb = (unsigned short*)(ws + OFF_WQ);   // [1024][512] = wq|wk
    unsigned short* WVb = WQb + 2 * 262144;
    unsigned short* WOb = WQb + 3 * 262144;
    float*          BQK = (float*)(ws + OFF_BQK);
    float*          RS  = (float*)(ws + OFF_RS);
    unsigned short* HT  = (unsigned short*)(ws + OFF_HT);
    unsigned short* QK  = (unsigned short*)(ws + OFF_QK);
    unsigned short* V   = (unsigned short*)(ws + OFF_V);
    unsigned short* H2  = (unsigned short*)(ws + OFF_H2);
    unsigned short* P   = (unsigned short*)(ws + OFF_P);
    float*          GNP = (float*)(ws + OFF_GNP);

    const long LC  = 1048576;   // 2048*512
    const long LQK = 2097152;   // 2048*1024
    const long LL  = 4194304;   // 2048*2048

    weights_to_bf16<<<1028, 256, 0, stream>>>(
        (const float4*)wq, (const float4*)wk, (const float4*)wv, (const float4*)wo,
        bq, bk, (ushort4v*)WQb, BQK);

    gn_partial<<<1024, 256, 0, stream>>>(x, GNP);
    norm_transpose<<<dim3(32, 8, 8), 256, 0, stream>>>(x, GNP, gamma, beta, HT);

    // fused q|k projection (M=2048,N=1024,K=512) -- 8-phase 256^2, 256 wgs
    gemm256<unsigned short, 1><<<dim3(4, 8, 8), 512, 0, stream>>>(
        HT, WQb, QK, 512, 512, 512, 1024, LC, 0, LQK, BQK, nullptr, 0, 1.0f);
    // v[o,l]  (M=512,N=2048,K=512)
    gemm_nt<unsigned short, 2><<<dim3(16, 4, 8), 256, 0, stream>>>(
        WVb, HT, V, 512, 512, 512, 2048, 0, LC, LC, bv, nullptr, 0, nullptr, 0, 1.0f);

    // P = exp(q.k/sqrt(C)) + per-block row-sum partials (M=N=2048,K=512)
    gemm256<unsigned short, 4><<<dim3(8, 8, 8), 512, 0, stream>>>(
        QK, QK + 512, P, 512, 1024, 1024, 2048, LQK, LQK, LL,
        nullptr, RS, 16384, 0.04419417382f);

    // h2_t[i,c] = (sum_j P[i,j] v[c,j]) / rowsum[i]  (M=2048,N=512,K=2048)
    gemm_nt<unsigned short, 5><<<dim3(4, 16, 8), 256, 0, stream>>>(
        P, V, H2, 2048, 2048, 2048, 512, LL, LC, LC, nullptr, nullptr, 0, RS, 16384, 1.0f);

    // out[o,l] = sum_c wo[o,c] h2_t[l,c] + bo[o] + x[o,l]  (M=512,N=2048,K=512)
    gemm_nt<float, 3><<<dim3(16, 4, 8), 256, 0, stream>>>(
        WOb, H2, out, 512, 512, 512, 2048, 0, LC, LC, bo, x, LC, nullptr, 0, 1.0f);
}